// Round 8
// baseline (288.529 us; speedup 1.0000x reference)
//
#include <hip/hip_runtime.h>
#include <hip/hip_bf16.h>

// MambaBlock: B=2, L=1024, dim=1024, d_inner=2048, DT_RANK=64, D_STATE=16
// Inputs fp32, output fp32. Intermediates xz/u/y bf16; scan state fp32.
// MFMA GEMMs: 64x128 tile, BK=32, 3-buf 2-ahead prefetch, counted vmcnt(3),
// XCD-aware block swizzle. conv+SiLU fused into xproj_splitk (32 K-slices).
// dt-GEMM fused into scan as a per-block 32x128 mini-MFMA (dtl in LDS).
// Scan: 2 threads/channel (8 states each), LC=32, NCHUNK=32.
// 9 dispatches total.
//
// ws layout (float units):
//   xn_b  (bf16 2048x1024) : @0          1,048,576
//   xz_b  (bf16 2048x4096) : @1,048,576  4,194,304   } opart (fp32 4x2,097,152)
//   u_b   (bf16 2048x2048) : @5,242,880  2,097,152   }   aliases xz_b..xdbl
//   xdbl  (fp32 2048x96)   : @7,340,032    196,608   }   dead after scan_part2
//   (gap)                  : @7,536,640  2,097,152   }
//   hpart (fp32 32x65536)  : @9,633,792  2,097,152   } xpart 32x196608=6.29M
//   Aprod (fp32 32x65536)  : @13,828,096 2,097,152   }   aliases hpart..hinit
//   hinit (fp32 32x65536)  : @18,022,400 2,097,152   }   (dead until scan)
//   y_b   (bf16 2048x2048) : @22,216,704 2,097,152
//   w_in_b (bf16)          : @24,313,856 2,097,152
//   w_out_b(bf16)          : @26,411,008 1,048,576
//   w_dt_b (bf16)          : @27,459,584    65,536
// total < 27,590,656 fu = 110 MB (ws = 256 MiB)

#define LC 32
#define NCHUNK 32

typedef short bf16x8 __attribute__((ext_vector_type(8)));
typedef float f32x4  __attribute__((ext_vector_type(4)));

static __device__ __forceinline__ float siluf(float x) { return x / (1.f + __expf(-x)); }
static __device__ __forceinline__ unsigned short f2bf(float f) {
    unsigned int u = __float_as_uint(f);
    unsigned int r = (u + 0x7fffu + ((u >> 16) & 1u)) >> 16;
    return (unsigned short)r;
}
static __device__ __forceinline__ float bfb(unsigned short u) {
    return __uint_as_float(((unsigned int)u) << 16);
}
// async global->LDS, 16 B per lane; LDS dest = wave-uniform base + lane*16
static __device__ __forceinline__ void gload_lds16(const void* g, void* l) {
    __builtin_amdgcn_global_load_lds(
        (const __attribute__((address_space(1))) void*)g,
        (__attribute__((address_space(3))) void*)l, 16, 0, 0);
}

// ---------------- fused setup: weight converts + LayerNorm ----------------
// blocks [0,6272): w_in/w_out/w_dt fp32->bf16;  blocks [6272,8320): LN row m
__global__ __launch_bounds__(256) void setup_kernel(
    const float* __restrict__ w_in,  unsigned short* __restrict__ w_in_b,
    const float* __restrict__ w_out, unsigned short* __restrict__ w_out_b,
    const float* __restrict__ w_dt,  unsigned short* __restrict__ w_dt_b,
    const float* __restrict__ x,
    const float* __restrict__ ln_w,
    const float* __restrict__ ln_b,
    unsigned short* __restrict__ xn)
{
    int bid = blockIdx.x, tid = threadIdx.x;
    if (bid < 6272) {
        int i = bid * 256 + tid;
        const float* in; unsigned short* outp; int j;
        if (i < 1048576)      { in = w_in;  outp = w_in_b;  j = i; }
        else if (i < 1572864) { in = w_out; outp = w_out_b; j = i - 1048576; }
        else if (i < 1605632) { in = w_dt;  outp = w_dt_b;  j = i - 1572864; }
        else return;
        float4 v = reinterpret_cast<const float4*>(in)[j];
        ushort4 o = { f2bf(v.x), f2bf(v.y), f2bf(v.z), f2bf(v.w) };
        reinterpret_cast<ushort4*>(outp)[j] = o;
        return;
    }
    int m = bid - 6272;
    const float4* xr = reinterpret_cast<const float4*>(x) + (size_t)m * 256;
    float4 r = xr[tid];
    float f0 = r.x, f1 = r.y, f2 = r.z, f3 = r.w;
    float s  = f0 + f1 + f2 + f3;
    float s2 = f0*f0 + f1*f1 + f2*f2 + f3*f3;
    #pragma unroll
    for (int off = 32; off > 0; off >>= 1) {
        s  += __shfl_down(s, off);
        s2 += __shfl_down(s2, off);
    }
    __shared__ float red[8];
    if ((tid & 63) == 0) { red[tid >> 6] = s; red[4 + (tid >> 6)] = s2; }
    __syncthreads();
    float st = red[0] + red[1] + red[2] + red[3];
    float qt = red[4] + red[5] + red[6] + red[7];
    float mu   = st * (1.f / 1024.f);
    float var  = qt * (1.f / 1024.f) - mu * mu;
    float rstd = rsqrtf(var + 1e-5f);
    float4 wv = reinterpret_cast<const float4*>(ln_w)[tid];
    float4 bv = reinterpret_cast<const float4*>(ln_b)[tid];
    ushort4 o = { f2bf((f0 - mu) * rstd * wv.x + bv.x),
                  f2bf((f1 - mu) * rstd * wv.y + bv.y),
                  f2bf((f2 - mu) * rstd * wv.z + bv.z),
                  f2bf((f3 - mu) * rstd * wv.w + bv.w) };
    reinterpret_cast<ushort4*>(xn + (size_t)m * 1024)[tid] = o;
}

// ---------------- bf16 MFMA GEMM-NT, 64x128 tile, 3-buf counted-vmcnt ----------
// 4 waves in 2x2 grid over (M=64, N=128); each wave 32x64 (acc[2][4]).
// XCD swizzle: contiguous tile chunk per XCD (grid %8==0 -> bijective).
// ep: 0 = fp32 raw -> C; 3 = raw -> Cb bf16
__global__ __launch_bounds__(256) void gemm_bf16_nt(
    const unsigned short* __restrict__ A, int lda,
    const unsigned short* __restrict__ B, int ldb,
    int Kslice,
    float* __restrict__ C, unsigned short* __restrict__ Cb, int ldc,
    int ep, size_t Cstride)
{
    __shared__ short As[3 * 64 * 32];    // 12 KB
    __shared__ short Bs[3 * 128 * 32];   // 24 KB
    int tid = threadIdx.x;
    int z = blockIdx.z;
    A += (size_t)z * Kslice;
    B += (size_t)z * Kslice;
    C += (size_t)z * Cstride;

    // XCD-aware swizzle over (x,y) tile grid
    int gx = gridDim.x;
    int wg = blockIdx.y * gx + blockIdx.x;
    int nwg = gx * gridDim.y;
    int cpx = nwg >> 3;
    int swz = (wg & 7) * cpx + (wg >> 3);
    int bx = swz % gx, by = swz / gx;

    int m0 = by * 64, n0 = bx * 128;
    int lane = tid & 63, wave = tid >> 6;
    int wm = (wave >> 1) * 32, wn = (wave & 1) * 64;
    int frow = lane & 15, fq = lane >> 4;

    f32x4 acc[2][4] = {};

    int lrow = lane >> 2;
    int scol = (lane & 3) * 8;
    const unsigned short* AgL = A + (size_t)(m0 + wave * 16 + lrow) * lda + scol;
    const unsigned short* BgL = B + (size_t)(n0 + wave * 16 + lrow) * ldb + scol;
    int aoff = (wave * 16) * 32;   // shorts
    int boff = (wave * 16) * 32;

    // prologue: stage buffers 0 and 1 (6 loads in flight per wave)
    #pragma unroll
    for (int p = 0; p < 2; ++p) {
        int nk = p * 32;
        gload_lds16(AgL + nk,                    As + p * 2048 + aoff);
        gload_lds16(BgL + nk,                    Bs + p * 4096 + boff);
        gload_lds16(BgL + (size_t)64 * ldb + nk, Bs + p * 4096 + boff + 64 * 32);
    }

    int cur = 0;
    for (int k0 = 0; k0 < Kslice; k0 += 32) {
        if (k0 + 32 < Kslice) {
            asm volatile("s_waitcnt vmcnt(3) lgkmcnt(0)" ::: "memory");
        } else {
            asm volatile("s_waitcnt vmcnt(0) lgkmcnt(0)" ::: "memory");
        }
        __builtin_amdgcn_s_barrier();
        int nk = k0 + 64;
        if (nk < Kslice) {
            int stg = cur - 1; if (stg < 0) stg = 2;   // (cur+2)%3
            gload_lds16(AgL + nk,                    As + stg * 2048 + aoff);
            gload_lds16(BgL + nk,                    Bs + stg * 4096 + boff);
            gload_lds16(BgL + (size_t)64 * ldb + nk, Bs + stg * 4096 + boff + 64 * 32);
        }
        const short* Ac = As + cur * 2048;
        const short* Bc = Bs + cur * 4096;
        bf16x8 af[2], bfr[4];
        #pragma unroll
        for (int i = 0; i < 2; ++i)
            af[i] = *reinterpret_cast<const bf16x8*>(Ac + (wm + i * 16 + frow) * 32 + fq * 8);
        #pragma unroll
        for (int j = 0; j < 4; ++j)
            bfr[j] = *reinterpret_cast<const bf16x8*>(Bc + (wn + j * 16 + frow) * 32 + fq * 8);
        #pragma unroll
        for (int i = 0; i < 2; ++i)
            #pragma unroll
            for (int j = 0; j < 4; ++j)
                acc[i][j] = __builtin_amdgcn_mfma_f32_16x16x32_bf16(af[i], bfr[j], acc[i][j], 0, 0, 0);
        cur = (cur == 2) ? 0 : cur + 1;
    }

    int cn = lane & 15, rq = (lane >> 4) * 4;
    #pragma unroll
    for (int i = 0; i < 2; ++i) {
        #pragma unroll
        for (int j = 0; j < 4; ++j) {
            #pragma unroll
            for (int r = 0; r < 4; ++r) {
                int row = m0 + wm + i * 16 + rq + r;
                int col = n0 + wn + j * 16 + cn;
                float v = acc[i][j][r];
                if (ep == 0) {
                    C[(size_t)row * ldc + col] = v;
                } else {
                    Cb[(size_t)row * ldc + col] = f2bf(v);
                }
            }
        }
    }
}

// ---------------- out = x + sum_z part[z] ----------------
__global__ __launch_bounds__(256) void out_reduce(
    const float* __restrict__ part, const float* __restrict__ x,
    float* __restrict__ out)
{
    int i = blockIdx.x * 256 + threadIdx.x;
    float4 s = reinterpret_cast<const float4*>(x)[i];
    #pragma unroll
    for (int z = 0; z < 4; ++z) {
        float4 p = reinterpret_cast<const float4*>(part + (size_t)z * 2097152)[i];
        s.x += p.x; s.y += p.y; s.z += p.z; s.w += p.w;
    }
    reinterpret_cast<float4*>(out)[i] = s;
}

// ---------------- xproj split-K with fused depthwise conv + SiLU ----------------
// 32 K-slices of 64 (grid 32x32 = 1024 blocks = 4/CU).
__global__ __launch_bounds__(256) void xproj_splitk(
    const unsigned short* __restrict__ xz,
    const float* __restrict__ cw,
    const float* __restrict__ cb,
    const float* __restrict__ B,
    unsigned short* __restrict__ u,
    float* __restrict__ part)
{
    __shared__ float As[16][68];
    __shared__ float Bs[16][100];
    int tid = threadIdx.x;
    int m0 = blockIdx.x * 64;
    int k0 = blockIdx.y * 64;
    int tx = tid & 15;
    int ty = tid >> 4;
    float acc[4][6] = {};
    int arow = tid >> 2, akg = (tid & 3) << 2;
    int brow1 = (256 + tid) >> 2, bkg1 = ((256 + tid) & 3) << 2;
    int m = m0 + arow;
    int l = m & 1023;

    for (int ks = 0; ks < 64; ks += 16) {
        int e0 = k0 + ks + akg;
        // --- fused conv+silu for 4 consecutive e at row m ---
        float xv[4][4];   // [kk][j]
        #pragma unroll
        for (int kk = 0; kk < 4; ++kk) {
            ushort4 t = make_ushort4(0, 0, 0, 0);
            if (l - 3 + kk >= 0)
                t = *reinterpret_cast<const ushort4*>(xz + (size_t)(m - 3 + kk) * 4096 + e0);
            xv[kk][0] = bfb(t.x); xv[kk][1] = bfb(t.y);
            xv[kk][2] = bfb(t.z); xv[kk][3] = bfb(t.w);
        }
        float4 cbv = *reinterpret_cast<const float4*>(cb + e0);
        float cbs[4] = { cbv.x, cbv.y, cbv.z, cbv.w };
        float res[4];
        #pragma unroll
        for (int j = 0; j < 4; ++j) {
            float4 w = *reinterpret_cast<const float4*>(cw + (size_t)(e0 + j) * 4);
            float a = cbs[j];
            a = fmaf(w.x, xv[0][j], a);
            a = fmaf(w.y, xv[1][j], a);
            a = fmaf(w.z, xv[2][j], a);
            a = fmaf(w.w, xv[3][j], a);
            res[j] = siluf(a);
        }
        ushort4 uo = { f2bf(res[0]), f2bf(res[1]), f2bf(res[2]), f2bf(res[3]) };
        *reinterpret_cast<ushort4*>(u + (size_t)m * 2048 + e0) = uo;

        // --- B (w_xproj) loads ---
        float4 bv0 = make_float4(0.f, 0.f, 0.f, 0.f), bv1 = bv0;
        if (arow < 96)  bv0 = *reinterpret_cast<const float4*>(B + (size_t)arow * 2048 + k0 + ks + akg);
        if (brow1 < 96) bv1 = *reinterpret_cast<const float4*>(B + (size_t)brow1 * 2048 + k0 + ks + bkg1);
        __syncthreads();
        As[akg + 0][arow] = res[0]; As[akg + 1][arow] = res[1];
        As[akg + 2][arow] = res[2]; As[akg + 3][arow] = res[3];
        if (arow < 96) {
            Bs[akg + 0][arow] = bv0.x; Bs[akg + 1][arow] = bv0.y;
            Bs[akg + 2][arow] = bv0.z; Bs[akg + 3][arow] = bv0.w;
        }
        if (brow1 < 96) {
            Bs[bkg1 + 0][brow1] = bv1.x; Bs[bkg1 + 1][brow1] = bv1.y;
            Bs[bkg1 + 2][brow1] = bv1.z; Bs[bkg1 + 3][brow1] = bv1.w;
        }
        __syncthreads();
        #pragma unroll
        for (int k = 0; k < 16; ++k) {
            float aa[4], bb[6];
            #pragma unroll
            for (int i = 0; i < 4; ++i) aa[i] = As[k][ty * 4 + i];
            #pragma unroll
            for (int j = 0; j < 6; ++j) bb[j] = Bs[k][tx * 6 + j];
            #pragma unroll
            for (int i = 0; i < 4; ++i)
                #pragma unroll
                for (int j = 0; j < 6; ++j)
                    acc[i][j] = fmaf(aa[i], bb[j], acc[i][j]);
        }
    }
    float* p = part + (size_t)blockIdx.y * 196608;
    #pragma unroll
    for (int i = 0; i < 4; ++i)
        #pragma unroll
        for (int j = 0; j < 6; ++j)
            p[(size_t)(m0 + ty * 4 + i) * 96 + tx * 6 + j] = acc[i][j];
}

// reduce 32 partials -> xdbl fp32
__global__ __launch_bounds__(256) void xproj_reduce(
    const float* __restrict__ part, float* __restrict__ xdbl)
{
    int i = blockIdx.x * 256 + threadIdx.x;   // 196608
    float s = 0.f;
    #pragma unroll
    for (int sd = 0; sd < 32; ++sd) s += part[(size_t)sd * 196608 + i];
    xdbl[i] = s;
}

// ---- fused dt tile: dtl[32 l][128 e] = softplus(bf16(xdbl[:, :64]) @ w_dt^T + b_dt)
// 8 MFMAs per wave (2 l-frags x 2 e-frags x 2 k); bf16-rounded result in LDS.
static __device__ __forceinline__ void dt_tile128(
    const float* __restrict__ xdbl, const unsigned short* __restrict__ w_dt_b,
    const float* __restrict__ b_dt, size_t rbase, int et,
    int lane, int wave, float dtl[LC][128])
{
    int frow = lane & 15, fq = lane >> 4;
    bf16x8 af[2][2];
    #pragma unroll
    for (int i = 0; i < 2; ++i)
        #pragma unroll
        for (int kk = 0; kk < 2; ++kk) {
            const float* ap = xdbl + (rbase + i * 16 + frow) * 96 + kk * 32 + fq * 8;
            float4 a0 = *reinterpret_cast<const float4*>(ap);
            float4 a1 = *reinterpret_cast<const float4*>(ap + 4);
            bf16x8 t;
            t[0] = (short)f2bf(a0.x); t[1] = (short)f2bf(a0.y);
            t[2] = (short)f2bf(a0.z); t[3] = (short)f2bf(a0.w);
            t[4] = (short)f2bf(a1.x); t[5] = (short)f2bf(a1.y);
            t[6] = (short)f2bf(a1.z); t[7] = (short)f2bf(a1.w);
            af[i][kk] = t;
        }
    f32x4 dacc[2][2] = {};
    #pragma unroll
    for (int j = 0; j < 2; ++j)
        #pragma unroll
        for (int kk = 0; kk < 2; ++kk) {
            int row_e = et * 128 + wave * 32 + j * 16 + frow;
            bf16x8 bfr = *reinterpret_cast<const bf16x8*>(
                w_dt_b + (size_t)row_e * 64 + kk * 32 + fq * 8);
            #pragma unroll
            for (int i = 0; i < 2; ++i)
                dacc[i][j] = __builtin_amdgcn_mfma_f32_16x16x32_bf16(af[i][kk], bfr, dacc[i][j], 0, 0, 0);
        }
    int cn = lane & 15, rq = (lane >> 4) * 4;
    #pragma unroll
    for (int i = 0; i < 2; ++i)
        #pragma unroll
        for (int j = 0; j < 2; ++j)
            #pragma unroll
            for (int r = 0; r < 4; ++r) {
                int row = i * 16 + rq + r;             // 0..31 (l)
                int col = wave * 32 + j * 16 + cn;     // 0..127 (e)
                float v = dacc[i][j][r] + b_dt[et * 128 + col];
                v = (v > 20.f) ? v : log1pf(__expf(v));
                dtl[row][col] = bfb(f2bf(v));
            }
}

// ---------------- Chunked selective scan: 2 threads/channel, 8 states ----------
// grid 1024 = (b:2) x (et:16) x (c:32); 256 threads = 128 ch x 2 ngroups.
// A folded with log2(e): d = exp2(dt * A2). dt from per-block mini-MFMA tile.
__global__ __launch_bounds__(256) void scan_part1(
    const unsigned short* __restrict__ u,
    const float* __restrict__ xdbl,
    const unsigned short* __restrict__ w_dt_b,
    const float* __restrict__ b_dt,
    const float* __restrict__ a_log,
    float* __restrict__ hpart,
    float* __restrict__ Aprod)
{
    __shared__ float dtl[LC][128];
    int tid = threadIdx.x;
    int lane = tid & 63, wave = tid >> 6;
    int bid = blockIdx.x;
    int c = bid & 31, et = (bid >> 5) & 15, b = bid >> 9;
    int ch = tid >> 1, ng = tid & 1;
    int e = et * 128 + ch;
    size_t rbase = (size_t)b * 1024 + c * LC;

    dt_tile128(xdbl, w_dt_b, b_dt, rbase, et, lane, wave, dtl);

    const float L2E = 1.4426950408889634f;
    float A2[8];
    {
        float4 a0 = *reinterpret_cast<const float4*>(a_log + (size_t)e * 16 + ng * 8);
        float4 a1 = *reinterpret_cast<const float4*>(a_log + (size_t)e * 16 + ng * 8 + 4);
        A2[0] = -__expf(a0.x) * L2E; A2[1] = -__expf(a0.y) * L2E;
        A2[2] = -__expf(a0.z) * L2E; A2[3] = -__expf(a0.w) * L2E;
        A2[4] = -__expf(a1.x) * L2E; A2[5] = -__expf(a1.y) * L2E;
        A2[6] = -__expf(a1.z) * L2E; A2[7] = -__expf(a1.w) * L2E;
    }
    float h[8], P[8];
    #pragma unroll
    for (int n = 0; n < 8; ++n) { h[n] = 0.f; P[n] = 1.f; }

    const unsigned short* u_p = u + rbase * 2048 + e;
    const float* b_p = xdbl + rbase * 96 + 64 + ng * 8;
    __syncthreads();
    #pragma unroll 8
    for (int l = 0; l < LC; ++l) {
        float dtv = dtl[l][ch];
        float u_c = bfb(u_p[(size_t)l * 2048]);
        float4 b0 = *reinterpret_cast<const float4*>(b_p + (size_t)l * 96);
        float4 b1 = *reinterpret_cast<const float4*>(b_p + (size_t)l * 96 + 4);
        float Bv[8] = { b0.x, b0.y, b0.z, b0.w, b1.x, b1.y, b1.z, b1.w };
        float du = dtv * u_c;
        #pragma unroll
        for (int n = 0; n < 8; ++n) {
            float d = exp2f(dtv * A2[n]);
            h[n] = fmaf(d, h[n], du * Bv[n]);
            P[n] *= d;
        }
    }
    size_t oidx = (size_t)c * 65536 + ((size_t)b * 2048 + e) * 16 + ng * 8;
    *reinterpret_cast<float4*>(hpart + oidx)     = make_float4(h[0], h[1], h[2], h[3]);
    *reinterpret_cast<float4*>(hpart + oidx + 4) = make_float4(h[4], h[5], h[6], h[7]);
    *reinterpret_cast<float4*>(Aprod + oidx)     = make_float4(P[0], P[1], P[2], P[3]);
    *reinterpret_cast<float4*>(Aprod + oidx + 4) = make_float4(P[4], P[5], P[6], P[7]);
}

// 65536 scalar chains, 1 float/thread -> 256 blocks (all CUs busy)
__global__ __launch_bounds__(256) void scan_combine(
    const float* __restrict__ hpart,
    const float* __restrict__ Aprod,
    float* __restrict__ hinit)
{
    int t = blockIdx.x * 256 + threadIdx.x;   // 65536 threads x 1 float
    float h = 0.f;
    #pragma unroll 8
    for (int c = 0; c < NCHUNK; ++c) {
        hinit[(size_t)c * 65536 + t] = h;
        float P  = Aprod[(size_t)c * 65536 + t];
        float hp = hpart[(size_t)c * 65536 + t];
        h = fmaf(P, h, hp);
    }
}

__global__ __launch_bounds__(256) void scan_part2(
    const unsigned short* __restrict__ u,
    const float* __restrict__ xdbl,
    const unsigned short* __restrict__ w_dt_b,
    const float* __restrict__ b_dt,
    const unsigned short* __restrict__ xz,
    const float* __restrict__ a_log,
    const float* __restrict__ d_skip,
    const float* __restrict__ hinit,
    unsigned short* __restrict__ y)
{
    __shared__ float dtl[LC][128];
    int tid = threadIdx.x;
    int lane = tid & 63, wave = tid >> 6;
    int bid = blockIdx.x;
    int c = bid & 31, et = (bid >> 5) & 15, b = bid >> 9;
    int ch = tid >> 1, ng = tid & 1;
    int e = et * 128 + ch;
    size_t rbase = (size_t)b * 1024 + c * LC;

    dt_tile128(xdbl, w_dt_b, b_dt, rbase, et, lane, wave, dtl);

    const float L2E = 1.4426950408889634f;
    float A2[8];
    {
        float4 a0 = *reinterpret_cast<const float4*>(a_log + (size_t)e * 16 + ng * 8);
        float4 a1 = *reinterpret_cast<const float4*>(a_log + (size_t)e * 16 + ng * 8 + 4);
        A2[0] = -__expf(a0.x) * L2E; A2[1] = -__expf(a0.y) * L2E;
        A2[2] = -__expf(a0.z) * L2E; A2[3] = -__expf(a0.w) * L2E;
        A2[4] = -__expf(a1.x) * L2E; A2[5] = -__expf(a1.y) * L2E;
        A2[6] = -__expf(a1.z) * L2E; A2[7] = -__expf(a1.w) * L2E;
    }
    float dsk = d_skip[e];
    float h[8];
    size_t oidx = (size_t)c * 65536 + ((size_t)b * 2048 + e) * 16 + ng * 8;
    {
        float4 h0 = *reinterpret_cast<const float4*>(hinit + oidx);
        float4 h1 = *reinterpret_cast<const float4*>(hinit + oidx + 4);
        h[0] = h0.x; h[1] = h0.y; h[2] = h0.z; h[3] = h0.w;
        h[4] = h1.x; h[5] = h1.y; h[6] = h1.z; h[7] = h1.w;
    }

    const unsigned short* u_p = u + rbase * 2048 + e;
    const unsigned short* z_p = xz + rbase * 4096 + 2048 + e;
    const float* b_p = xdbl + rbase * 96 + 64 + ng * 8;
    unsigned short* y_p = y + rbase * 2048 + e;
    __syncthreads();
    #pragma unroll 8
    for (int l = 0; l < LC; ++l) {
        float dtv = dtl[l][ch];
        float u_c = bfb(u_p[(size_t)l * 2048]);
        float4 b0 = *reinterpret_cast<const float4*>(b_p + (size_t)l * 96);
        float4 b1 = *reinterpret_cast<const float4*>(b_p + (size_t)l * 96 + 4);
        float4 c0 = *reinterpret_cast<const float4*>(b_p + (size_t)l * 96 + 16);
        float4 c1 = *reinterpret_cast<const float4*>(b_p + (size_t)l * 96 + 20);
        float Bv[8] = { b0.x, b0.y, b0.z, b0.w, b1.x, b1.y, b1.z, b1.w };
        float Cv[8] = { c0.x, c0.y, c0.z, c0.w, c1.x, c1.y, c1.z, c1.w };
        float du = dtv * u_c;
        float p = 0.f;
        #pragma unroll
        for (int n = 0; n < 8; ++n) {
            float d = exp2f(dtv * A2[n]);
            h[n] = fmaf(d, h[n], du * Bv[n]);
            p = fmaf(h[n], Cv[n], p);
        }
        p += __shfl_xor(p, 1);
        if (ng == 0) {
            float zv = bfb(z_p[(size_t)l * 4096]);
            y_p[(size_t)l * 2048] = f2bf((p + u_c * dsk) * siluf(zv));
        }
    }
}

extern "C" void kernel_launch(void* const* d_in, const int* in_sizes, int n_in,
                              void* d_out, int out_size, void* d_ws, size_t ws_size,
                              hipStream_t stream) {
    const float* x       = (const float*)d_in[0];
    const float* ln_w    = (const float*)d_in[1];
    const float* ln_b    = (const float*)d_in[2];
    const float* w_in    = (const float*)d_in[3];
    const float* conv_w  = (const float*)d_in[4];
    const float* conv_b  = (const float*)d_in[5];
    const float* w_xproj = (const float*)d_in[6];
    const float* w_dt    = (const float*)d_in[7];
    const float* b_dt    = (const float*)d_in[8];
    const float* a_log   = (const float*)d_in[9];
    const float* d_skip  = (const float*)d_in[10];
    const float* w_out   = (const float*)d_in[11];
    float* out = (float*)d_out;

    float* ws = (float*)d_ws;
    unsigned short* xn_b    = (unsigned short*)(ws);
    unsigned short* xz_b    = (unsigned short*)(ws + 1048576);
    unsigned short* u_b     = (unsigned short*)(ws + 5242880);
    float* xdbl  = ws + 7340032;
    float* hpart = ws + 9633792;
    float* Aprod = ws + 13828096;
    float* hinit = ws + 18022400;
    unsigned short* y_b     = (unsigned short*)(ws + 22216704);
    unsigned short* w_in_b  = (unsigned short*)(ws + 24313856);
    unsigned short* w_out_b = (unsigned short*)(ws + 26411008);
    unsigned short* w_dt_b  = (unsigned short*)(ws + 27459584);
    float* xpart = ws + 9633792;    // 32x196608, aliases hpart..hinit (dead until scan)
    float* opart = ws + 1048576;    // aliases xz_b..xdbl (dead after part2)

    // 0. weight converts + LayerNorm, one launch
    setup_kernel<<<8320, 256, 0, stream>>>(w_in, w_in_b, w_out, w_out_b, w_dt, w_dt_b,
                                           x, ln_w, ln_b, xn_b);
    // 1. xz = xn @ w_in^T  (2048 x 4096 x 1024)  MFMA 64x128 -> bf16
    gemm_bf16_nt<<<dim3(32, 32, 1), 256, 0, stream>>>(xn_b, 1024, w_in_b, 1024, 1024,
                                                      nullptr, xz_b, 4096, 3, 0);
    // 2+3. fused conv+silu -> u (side output) + x_dbl split-K partials (32 slices)
    xproj_splitk<<<dim3(32, 32), 256, 0, stream>>>(xz_b, conv_w, conv_b, w_xproj,
                                                   u_b, xpart);
    xproj_reduce<<<768, 256, 0, stream>>>(xpart, xdbl);
    // 4+5. chunked selective scan (LC=32, 32 chunks), 2 thr/channel, dt fused
    scan_part1<<<1024, 256, 0, stream>>>(u_b, xdbl, w_dt_b, b_dt, a_log, hpart, Aprod);
    scan_combine<<<256, 256, 0, stream>>>(hpart, Aprod, hinit);
    scan_part2<<<1024, 256, 0, stream>>>(u_b, xdbl, w_dt_b, b_dt, xz_b, a_log,
                                         d_skip, hinit, y_b);
    // 6. out-proj split-K x4 (fp32 partials) + reduce(+residual)
    gemm_bf16_nt<<<dim3(8, 32, 4), 256, 0, stream>>>(y_b, 2048, w_out_b, 2048, 512,
                                                     opart, nullptr, 1024, 0, 2097152);
    out_reduce<<<2048, 256, 0, stream>>>(opart, x, out);
}

// Round 9
// 274.091 us; speedup vs baseline: 1.0527x; 1.0527x over previous
//
#include <hip/hip_runtime.h>
#include <hip/hip_bf16.h>

// MambaBlock: B=2, L=1024, dim=1024, d_inner=2048, DT_RANK=64, D_STATE=16
// Inputs fp32, output fp32. Intermediates xz/u/y bf16; scan state fp32.
// MFMA GEMMs: 64x128 tile, BK=32, 3-buf 2-ahead prefetch, counted vmcnt(3),
// XCD-aware block swizzle. conv+SiLU fused into xproj_splitk (32 K-slices).
// dt-GEMM fused into scan as a per-block 16x128 mini-MFMA (dtl in LDS).
// Scan: 2 threads/channel (8 states each), LC=16, NCHUNK=64 (8 blocks/CU),
// B/C chunk rows staged in LDS (inner loop = LDS reads + 1 VMEM).
// 9 dispatches total.
//
// ws layout (float units):
//   xn_b  (bf16 2048x1024) : @0          1,048,576
//   xz_b  (bf16 2048x4096) : @1,048,576  4,194,304   } opart (fp32 4x2,097,152)
//   u_b   (bf16 2048x2048) : @5,242,880  2,097,152   }   aliases xz_b..xdbl
//   xdbl  (fp32 2048x96)   : @7,340,032    196,608   }   dead after scan_part2
//   (gap)                  : @7,536,640  2,097,152   }
//   hpart (fp32 64x65536)  : @9,633,792  4,194,304   } xpart 32x196608=6.29M
//   Aprod (fp32 64x65536)  : @13,828,096 4,194,304   }   aliases hpart+Aprod
//   hinit (fp32 64x65536)  : @18,022,400 4,194,304   }   (dead until scan)
//   y_b   (bf16 2048x2048) : @22,216,704 2,097,152
//   w_in_b (bf16)          : @24,313,856 2,097,152
//   w_out_b(bf16)          : @26,411,008 1,048,576
//   w_dt_b (bf16)          : @27,459,584    65,536
// total < 27,590,656 fu = 110 MB (ws = 256 MiB)

#define LC 16
#define NCHUNK 64

typedef short bf16x8 __attribute__((ext_vector_type(8)));
typedef float f32x4  __attribute__((ext_vector_type(4)));

static __device__ __forceinline__ float siluf(float x) { return x / (1.f + __expf(-x)); }
static __device__ __forceinline__ unsigned short f2bf(float f) {
    unsigned int u = __float_as_uint(f);
    unsigned int r = (u + 0x7fffu + ((u >> 16) & 1u)) >> 16;
    return (unsigned short)r;
}
static __device__ __forceinline__ float bfb(unsigned short u) {
    return __uint_as_float(((unsigned int)u) << 16);
}
// async global->LDS, 16 B per lane; LDS dest = wave-uniform base + lane*16
static __device__ __forceinline__ void gload_lds16(const void* g, void* l) {
    __builtin_amdgcn_global_load_lds(
        (const __attribute__((address_space(1))) void*)g,
        (__attribute__((address_space(3))) void*)l, 16, 0, 0);
}

// ---------------- fused setup: weight converts + LayerNorm ----------------
// blocks [0,6272): w_in/w_out/w_dt fp32->bf16;  blocks [6272,8320): LN row m
__global__ __launch_bounds__(256) void setup_kernel(
    const float* __restrict__ w_in,  unsigned short* __restrict__ w_in_b,
    const float* __restrict__ w_out, unsigned short* __restrict__ w_out_b,
    const float* __restrict__ w_dt,  unsigned short* __restrict__ w_dt_b,
    const float* __restrict__ x,
    const float* __restrict__ ln_w,
    const float* __restrict__ ln_b,
    unsigned short* __restrict__ xn)
{
    int bid = blockIdx.x, tid = threadIdx.x;
    if (bid < 6272) {
        int i = bid * 256 + tid;
        const float* in; unsigned short* outp; int j;
        if (i < 1048576)      { in = w_in;  outp = w_in_b;  j = i; }
        else if (i < 1572864) { in = w_out; outp = w_out_b; j = i - 1048576; }
        else if (i < 1605632) { in = w_dt;  outp = w_dt_b;  j = i - 1572864; }
        else return;
        float4 v = reinterpret_cast<const float4*>(in)[j];
        ushort4 o = { f2bf(v.x), f2bf(v.y), f2bf(v.z), f2bf(v.w) };
        reinterpret_cast<ushort4*>(outp)[j] = o;
        return;
    }
    int m = bid - 6272;
    const float4* xr = reinterpret_cast<const float4*>(x) + (size_t)m * 256;
    float4 r = xr[tid];
    float f0 = r.x, f1 = r.y, f2 = r.z, f3 = r.w;
    float s  = f0 + f1 + f2 + f3;
    float s2 = f0*f0 + f1*f1 + f2*f2 + f3*f3;
    #pragma unroll
    for (int off = 32; off > 0; off >>= 1) {
        s  += __shfl_down(s, off);
        s2 += __shfl_down(s2, off);
    }
    __shared__ float red[8];
    if ((tid & 63) == 0) { red[tid >> 6] = s; red[4 + (tid >> 6)] = s2; }
    __syncthreads();
    float st = red[0] + red[1] + red[2] + red[3];
    float qt = red[4] + red[5] + red[6] + red[7];
    float mu   = st * (1.f / 1024.f);
    float var  = qt * (1.f / 1024.f) - mu * mu;
    float rstd = rsqrtf(var + 1e-5f);
    float4 wv = reinterpret_cast<const float4*>(ln_w)[tid];
    float4 bv = reinterpret_cast<const float4*>(ln_b)[tid];
    ushort4 o = { f2bf((f0 - mu) * rstd * wv.x + bv.x),
                  f2bf((f1 - mu) * rstd * wv.y + bv.y),
                  f2bf((f2 - mu) * rstd * wv.z + bv.z),
                  f2bf((f3 - mu) * rstd * wv.w + bv.w) };
    reinterpret_cast<ushort4*>(xn + (size_t)m * 1024)[tid] = o;
}

// ---------------- bf16 MFMA GEMM-NT, 64x128 tile, 3-buf counted-vmcnt ----------
// 4 waves in 2x2 grid over (M=64, N=128); each wave 32x64 (acc[2][4]).
// XCD swizzle: contiguous tile chunk per XCD (grid %8==0 -> bijective).
// ep: 0 = fp32 raw -> C; 3 = raw -> Cb bf16
__global__ __launch_bounds__(256) void gemm_bf16_nt(
    const unsigned short* __restrict__ A, int lda,
    const unsigned short* __restrict__ B, int ldb,
    int Kslice,
    float* __restrict__ C, unsigned short* __restrict__ Cb, int ldc,
    int ep, size_t Cstride)
{
    __shared__ short As[3 * 64 * 32];    // 12 KB
    __shared__ short Bs[3 * 128 * 32];   // 24 KB
    int tid = threadIdx.x;
    int z = blockIdx.z;
    A += (size_t)z * Kslice;
    B += (size_t)z * Kslice;
    C += (size_t)z * Cstride;

    // XCD-aware swizzle over (x,y) tile grid
    int gx = gridDim.x;
    int wg = blockIdx.y * gx + blockIdx.x;
    int nwg = gx * gridDim.y;
    int cpx = nwg >> 3;
    int swz = (wg & 7) * cpx + (wg >> 3);
    int bx = swz % gx, by = swz / gx;

    int m0 = by * 64, n0 = bx * 128;
    int lane = tid & 63, wave = tid >> 6;
    int wm = (wave >> 1) * 32, wn = (wave & 1) * 64;
    int frow = lane & 15, fq = lane >> 4;

    f32x4 acc[2][4] = {};

    int lrow = lane >> 2;
    int scol = (lane & 3) * 8;
    const unsigned short* AgL = A + (size_t)(m0 + wave * 16 + lrow) * lda + scol;
    const unsigned short* BgL = B + (size_t)(n0 + wave * 16 + lrow) * ldb + scol;
    int aoff = (wave * 16) * 32;   // shorts
    int boff = (wave * 16) * 32;

    // prologue: stage buffers 0 and 1 (6 loads in flight per wave)
    #pragma unroll
    for (int p = 0; p < 2; ++p) {
        int nk = p * 32;
        gload_lds16(AgL + nk,                    As + p * 2048 + aoff);
        gload_lds16(BgL + nk,                    Bs + p * 4096 + boff);
        gload_lds16(BgL + (size_t)64 * ldb + nk, Bs + p * 4096 + boff + 64 * 32);
    }

    int cur = 0;
    for (int k0 = 0; k0 < Kslice; k0 += 32) {
        if (k0 + 32 < Kslice) {
            asm volatile("s_waitcnt vmcnt(3) lgkmcnt(0)" ::: "memory");
        } else {
            asm volatile("s_waitcnt vmcnt(0) lgkmcnt(0)" ::: "memory");
        }
        __builtin_amdgcn_s_barrier();
        int nk = k0 + 64;
        if (nk < Kslice) {
            int stg = cur - 1; if (stg < 0) stg = 2;   // (cur+2)%3
            gload_lds16(AgL + nk,                    As + stg * 2048 + aoff);
            gload_lds16(BgL + nk,                    Bs + stg * 4096 + boff);
            gload_lds16(BgL + (size_t)64 * ldb + nk, Bs + stg * 4096 + boff + 64 * 32);
        }
        const short* Ac = As + cur * 2048;
        const short* Bc = Bs + cur * 4096;
        bf16x8 af[2], bfr[4];
        #pragma unroll
        for (int i = 0; i < 2; ++i)
            af[i] = *reinterpret_cast<const bf16x8*>(Ac + (wm + i * 16 + frow) * 32 + fq * 8);
        #pragma unroll
        for (int j = 0; j < 4; ++j)
            bfr[j] = *reinterpret_cast<const bf16x8*>(Bc + (wn + j * 16 + frow) * 32 + fq * 8);
        #pragma unroll
        for (int i = 0; i < 2; ++i)
            #pragma unroll
            for (int j = 0; j < 4; ++j)
                acc[i][j] = __builtin_amdgcn_mfma_f32_16x16x32_bf16(af[i], bfr[j], acc[i][j], 0, 0, 0);
        cur = (cur == 2) ? 0 : cur + 1;
    }

    int cn = lane & 15, rq = (lane >> 4) * 4;
    #pragma unroll
    for (int i = 0; i < 2; ++i) {
        #pragma unroll
        for (int j = 0; j < 4; ++j) {
            #pragma unroll
            for (int r = 0; r < 4; ++r) {
                int row = m0 + wm + i * 16 + rq + r;
                int col = n0 + wn + j * 16 + cn;
                float v = acc[i][j][r];
                if (ep == 0) {
                    C[(size_t)row * ldc + col] = v;
                } else {
                    Cb[(size_t)row * ldc + col] = f2bf(v);
                }
            }
        }
    }
}

// ---------------- out = x + sum_z part[z] ----------------
__global__ __launch_bounds__(256) void out_reduce(
    const float* __restrict__ part, const float* __restrict__ x,
    float* __restrict__ out)
{
    int i = blockIdx.x * 256 + threadIdx.x;
    float4 s = reinterpret_cast<const float4*>(x)[i];
    #pragma unroll
    for (int z = 0; z < 4; ++z) {
        float4 p = reinterpret_cast<const float4*>(part + (size_t)z * 2097152)[i];
        s.x += p.x; s.y += p.y; s.z += p.z; s.w += p.w;
    }
    reinterpret_cast<float4*>(out)[i] = s;
}

// ---------------- xproj split-K with fused depthwise conv + SiLU ----------------
// 32 K-slices of 64 (grid 32x32 = 1024 blocks = 4/CU).
__global__ __launch_bounds__(256) void xproj_splitk(
    const unsigned short* __restrict__ xz,
    const float* __restrict__ cw,
    const float* __restrict__ cb,
    const float* __restrict__ B,
    unsigned short* __restrict__ u,
    float* __restrict__ part)
{
    __shared__ float As[16][68];
    __shared__ float Bs[16][100];
    int tid = threadIdx.x;
    int m0 = blockIdx.x * 64;
    int k0 = blockIdx.y * 64;
    int tx = tid & 15;
    int ty = tid >> 4;
    float acc[4][6] = {};
    int arow = tid >> 2, akg = (tid & 3) << 2;
    int brow1 = (256 + tid) >> 2, bkg1 = ((256 + tid) & 3) << 2;
    int m = m0 + arow;
    int l = m & 1023;

    for (int ks = 0; ks < 64; ks += 16) {
        int e0 = k0 + ks + akg;
        // --- fused conv+silu for 4 consecutive e at row m ---
        float xv[4][4];   // [kk][j]
        #pragma unroll
        for (int kk = 0; kk < 4; ++kk) {
            ushort4 t = make_ushort4(0, 0, 0, 0);
            if (l - 3 + kk >= 0)
                t = *reinterpret_cast<const ushort4*>(xz + (size_t)(m - 3 + kk) * 4096 + e0);
            xv[kk][0] = bfb(t.x); xv[kk][1] = bfb(t.y);
            xv[kk][2] = bfb(t.z); xv[kk][3] = bfb(t.w);
        }
        float4 cbv = *reinterpret_cast<const float4*>(cb + e0);
        float cbs[4] = { cbv.x, cbv.y, cbv.z, cbv.w };
        float res[4];
        #pragma unroll
        for (int j = 0; j < 4; ++j) {
            float4 w = *reinterpret_cast<const float4*>(cw + (size_t)(e0 + j) * 4);
            float a = cbs[j];
            a = fmaf(w.x, xv[0][j], a);
            a = fmaf(w.y, xv[1][j], a);
            a = fmaf(w.z, xv[2][j], a);
            a = fmaf(w.w, xv[3][j], a);
            res[j] = siluf(a);
        }
        ushort4 uo = { f2bf(res[0]), f2bf(res[1]), f2bf(res[2]), f2bf(res[3]) };
        *reinterpret_cast<ushort4*>(u + (size_t)m * 2048 + e0) = uo;

        // --- B (w_xproj) loads ---
        float4 bv0 = make_float4(0.f, 0.f, 0.f, 0.f), bv1 = bv0;
        if (arow < 96)  bv0 = *reinterpret_cast<const float4*>(B + (size_t)arow * 2048 + k0 + ks + akg);
        if (brow1 < 96) bv1 = *reinterpret_cast<const float4*>(B + (size_t)brow1 * 2048 + k0 + ks + bkg1);
        __syncthreads();
        As[akg + 0][arow] = res[0]; As[akg + 1][arow] = res[1];
        As[akg + 2][arow] = res[2]; As[akg + 3][arow] = res[3];
        if (arow < 96) {
            Bs[akg + 0][arow] = bv0.x; Bs[akg + 1][arow] = bv0.y;
            Bs[akg + 2][arow] = bv0.z; Bs[akg + 3][arow] = bv0.w;
        }
        if (brow1 < 96) {
            Bs[bkg1 + 0][brow1] = bv1.x; Bs[bkg1 + 1][brow1] = bv1.y;
            Bs[bkg1 + 2][brow1] = bv1.z; Bs[bkg1 + 3][brow1] = bv1.w;
        }
        __syncthreads();
        #pragma unroll
        for (int k = 0; k < 16; ++k) {
            float aa[4], bb[6];
            #pragma unroll
            for (int i = 0; i < 4; ++i) aa[i] = As[k][ty * 4 + i];
            #pragma unroll
            for (int j = 0; j < 6; ++j) bb[j] = Bs[k][tx * 6 + j];
            #pragma unroll
            for (int i = 0; i < 4; ++i)
                #pragma unroll
                for (int j = 0; j < 6; ++j)
                    acc[i][j] = fmaf(aa[i], bb[j], acc[i][j]);
        }
    }
    float* p = part + (size_t)blockIdx.y * 196608;
    #pragma unroll
    for (int i = 0; i < 4; ++i)
        #pragma unroll
        for (int j = 0; j < 6; ++j)
            p[(size_t)(m0 + ty * 4 + i) * 96 + tx * 6 + j] = acc[i][j];
}

// reduce 32 partials -> xdbl fp32
__global__ __launch_bounds__(256) void xproj_reduce(
    const float* __restrict__ part, float* __restrict__ xdbl)
{
    int i = blockIdx.x * 256 + threadIdx.x;   // 196608
    float s = 0.f;
    #pragma unroll
    for (int sd = 0; sd < 32; ++sd) s += part[(size_t)sd * 196608 + i];
    xdbl[i] = s;
}

// ---- fused dt tile: dtl[16 l][128 e] = softplus(bf16(xdbl[:, :64]) @ w_dt^T + b_dt)
// 4 MFMAs per wave (2 e-frags x 2 k); bf16-rounded result in LDS.
static __device__ __forceinline__ void dt_tile16(
    const float* __restrict__ xdbl, const unsigned short* __restrict__ w_dt_b,
    const float* __restrict__ b_dt, size_t rbase, int et,
    int lane, int wave, float dtl[LC][128])
{
    int frow = lane & 15, fq = lane >> 4;
    bf16x8 af[2];
    #pragma unroll
    for (int kk = 0; kk < 2; ++kk) {
        const float* ap = xdbl + (rbase + frow) * 96 + kk * 32 + fq * 8;
        float4 a0 = *reinterpret_cast<const float4*>(ap);
        float4 a1 = *reinterpret_cast<const float4*>(ap + 4);
        bf16x8 t;
        t[0] = (short)f2bf(a0.x); t[1] = (short)f2bf(a0.y);
        t[2] = (short)f2bf(a0.z); t[3] = (short)f2bf(a0.w);
        t[4] = (short)f2bf(a1.x); t[5] = (short)f2bf(a1.y);
        t[6] = (short)f2bf(a1.z); t[7] = (short)f2bf(a1.w);
        af[kk] = t;
    }
    f32x4 dacc[2] = {};
    #pragma unroll
    for (int j = 0; j < 2; ++j)
        #pragma unroll
        for (int kk = 0; kk < 2; ++kk) {
            int row_e = et * 128 + wave * 32 + j * 16 + frow;
            bf16x8 bfr = *reinterpret_cast<const bf16x8*>(
                w_dt_b + (size_t)row_e * 64 + kk * 32 + fq * 8);
            dacc[j] = __builtin_amdgcn_mfma_f32_16x16x32_bf16(af[kk], bfr, dacc[j], 0, 0, 0);
        }
    int cn = lane & 15, rq = (lane >> 4) * 4;
    #pragma unroll
    for (int j = 0; j < 2; ++j)
        #pragma unroll
        for (int r = 0; r < 4; ++r) {
            int row = rq + r;                      // 0..15 (l)
            int col = wave * 32 + j * 16 + cn;     // 0..127 (e)
            float v = dacc[j][r] + b_dt[et * 128 + col];
            v = (v > 20.f) ? v : log1pf(__expf(v));
            dtl[row][col] = bfb(f2bf(v));
        }
}

// ---------------- Chunked selective scan: 2 threads/channel, 8 states ----------
// grid 2048 = (b:2) x (et:16) x (c:64); 256 threads = 128 ch x 2 ngroups.
// 8 blocks/CU. B (and C) chunk rows staged in LDS; inner loop: 1 VMEM + LDS.
// A folded with log2(e): d = exp2(dt * A2). dt from per-block mini-MFMA tile.
__global__ __launch_bounds__(256) void scan_part1(
    const unsigned short* __restrict__ u,
    const float* __restrict__ xdbl,
    const unsigned short* __restrict__ w_dt_b,
    const float* __restrict__ b_dt,
    const float* __restrict__ a_log,
    float* __restrict__ hpart,
    float* __restrict__ Aprod)
{
    __shared__ float dtl[LC][128];
    __shared__ float Bl[LC][16];
    int tid = threadIdx.x;
    int lane = tid & 63, wave = tid >> 6;
    int bid = blockIdx.x;
    int c = bid & 63, et = (bid >> 6) & 15, b = bid >> 10;
    int ch = tid >> 1, ng = tid & 1;
    int e = et * 128 + ch;
    size_t rbase = (size_t)b * 1024 + c * LC;

    // stage B rows: 16 l x 16 states, one float per thread
    Bl[tid >> 4][tid & 15] = xdbl[(rbase + (tid >> 4)) * 96 + 64 + (tid & 15)];

    dt_tile16(xdbl, w_dt_b, b_dt, rbase, et, lane, wave, dtl);

    const float L2E = 1.4426950408889634f;
    float A2[8];
    {
        float4 a0 = *reinterpret_cast<const float4*>(a_log + (size_t)e * 16 + ng * 8);
        float4 a1 = *reinterpret_cast<const float4*>(a_log + (size_t)e * 16 + ng * 8 + 4);
        A2[0] = -__expf(a0.x) * L2E; A2[1] = -__expf(a0.y) * L2E;
        A2[2] = -__expf(a0.z) * L2E; A2[3] = -__expf(a0.w) * L2E;
        A2[4] = -__expf(a1.x) * L2E; A2[5] = -__expf(a1.y) * L2E;
        A2[6] = -__expf(a1.z) * L2E; A2[7] = -__expf(a1.w) * L2E;
    }
    float h[8], P[8];
    #pragma unroll
    for (int n = 0; n < 8; ++n) { h[n] = 0.f; P[n] = 1.f; }

    const unsigned short* u_p = u + rbase * 2048 + e;
    __syncthreads();
    #pragma unroll 8
    for (int l = 0; l < LC; ++l) {
        float dtv = dtl[l][ch];
        float u_c = bfb(u_p[(size_t)l * 2048]);
        float4 b0 = *reinterpret_cast<const float4*>(&Bl[l][ng * 8]);
        float4 b1 = *reinterpret_cast<const float4*>(&Bl[l][ng * 8 + 4]);
        float Bv[8] = { b0.x, b0.y, b0.z, b0.w, b1.x, b1.y, b1.z, b1.w };
        float du = dtv * u_c;
        #pragma unroll
        for (int n = 0; n < 8; ++n) {
            float d = exp2f(dtv * A2[n]);
            h[n] = fmaf(d, h[n], du * Bv[n]);
            P[n] *= d;
        }
    }
    size_t oidx = (size_t)c * 65536 + ((size_t)b * 2048 + e) * 16 + ng * 8;
    *reinterpret_cast<float4*>(hpart + oidx)     = make_float4(h[0], h[1], h[2], h[3]);
    *reinterpret_cast<float4*>(hpart + oidx + 4) = make_float4(h[4], h[5], h[6], h[7]);
    *reinterpret_cast<float4*>(Aprod + oidx)     = make_float4(P[0], P[1], P[2], P[3]);
    *reinterpret_cast<float4*>(Aprod + oidx + 4) = make_float4(P[4], P[5], P[6], P[7]);
}

// 65536 scalar chains, 1 float/thread -> 256 blocks (all CUs busy)
__global__ __launch_bounds__(256) void scan_combine(
    const float* __restrict__ hpart,
    const float* __restrict__ Aprod,
    float* __restrict__ hinit)
{
    int t = blockIdx.x * 256 + threadIdx.x;   // 65536 threads x 1 float
    float h = 0.f;
    #pragma unroll 8
    for (int c = 0; c < NCHUNK; ++c) {
        hinit[(size_t)c * 65536 + t] = h;
        float P  = Aprod[(size_t)c * 65536 + t];
        float hp = hpart[(size_t)c * 65536 + t];
        h = fmaf(P, h, hp);
    }
}

__global__ __launch_bounds__(256) void scan_part2(
    const unsigned short* __restrict__ u,
    const float* __restrict__ xdbl,
    const unsigned short* __restrict__ w_dt_b,
    const float* __restrict__ b_dt,
    const unsigned short* __restrict__ xz,
    const float* __restrict__ a_log,
    const float* __restrict__ d_skip,
    const float* __restrict__ hinit,
    unsigned short* __restrict__ y)
{
    __shared__ float dtl[LC][128];
    __shared__ float BCl[LC][32];
    int tid = threadIdx.x;
    int lane = tid & 63, wave = tid >> 6;
    int bid = blockIdx.x;
    int c = bid & 63, et = (bid >> 6) & 15, b = bid >> 10;
    int ch = tid >> 1, ng = tid & 1;
    int e = et * 128 + ch;
    size_t rbase = (size_t)b * 1024 + c * LC;

    // stage B+C rows: 16 l x 32 floats, two floats per thread
    #pragma unroll
    for (int s = 0; s < 2; ++s) {
        int idx = s * 256 + tid;   // < 512
        BCl[idx >> 5][idx & 31] = xdbl[(rbase + (idx >> 5)) * 96 + 64 + (idx & 31)];
    }

    dt_tile16(xdbl, w_dt_b, b_dt, rbase, et, lane, wave, dtl);

    const float L2E = 1.4426950408889634f;
    float A2[8];
    {
        float4 a0 = *reinterpret_cast<const float4*>(a_log + (size_t)e * 16 + ng * 8);
        float4 a1 = *reinterpret_cast<const float4*>(a_log + (size_t)e * 16 + ng * 8 + 4);
        A2[0] = -__expf(a0.x) * L2E; A2[1] = -__expf(a0.y) * L2E;
        A2[2] = -__expf(a0.z) * L2E; A2[3] = -__expf(a0.w) * L2E;
        A2[4] = -__expf(a1.x) * L2E; A2[5] = -__expf(a1.y) * L2E;
        A2[6] = -__expf(a1.z) * L2E; A2[7] = -__expf(a1.w) * L2E;
    }
    float dsk = d_skip[e];
    float h[8];
    size_t oidx = (size_t)c * 65536 + ((size_t)b * 2048 + e) * 16 + ng * 8;
    {
        float4 h0 = *reinterpret_cast<const float4*>(hinit + oidx);
        float4 h1 = *reinterpret_cast<const float4*>(hinit + oidx + 4);
        h[0] = h0.x; h[1] = h0.y; h[2] = h0.z; h[3] = h0.w;
        h[4] = h1.x; h[5] = h1.y; h[6] = h1.z; h[7] = h1.w;
    }

    const unsigned short* u_p = u + rbase * 2048 + e;
    const unsigned short* z_p = xz + rbase * 4096 + 2048 + e;
    unsigned short* y_p = y + rbase * 2048 + e;
    __syncthreads();
    #pragma unroll 8
    for (int l = 0; l < LC; ++l) {
        float dtv = dtl[l][ch];
        float u_c = bfb(u_p[(size_t)l * 2048]);
        float4 b0 = *reinterpret_cast<const float4*>(&BCl[l][ng * 8]);
        float4 b1 = *reinterpret_cast<const float4*>(&BCl[l][ng * 8 + 4]);
        float4 c0 = *reinterpret_cast<const float4*>(&BCl[l][16 + ng * 8]);
        float4 c1 = *reinterpret_cast<const float4*>(&BCl[l][16 + ng * 8 + 4]);
        float Bv[8] = { b0.x, b0.y, b0.z, b0.w, b1.x, b1.y, b1.z, b1.w };
        float Cv[8] = { c0.x, c0.y, c0.z, c0.w, c1.x, c1.y, c1.z, c1.w };
        float du = dtv * u_c;
        float p = 0.f;
        #pragma unroll
        for (int n = 0; n < 8; ++n) {
            float d = exp2f(dtv * A2[n]);
            h[n] = fmaf(d, h[n], du * Bv[n]);
            p = fmaf(h[n], Cv[n], p);
        }
        p += __shfl_xor(p, 1);
        if (ng == 0) {
            float zv = bfb(z_p[(size_t)l * 4096]);
            y_p[(size_t)l * 2048] = f2bf((p + u_c * dsk) * siluf(zv));
        }
    }
}

extern "C" void kernel_launch(void* const* d_in, const int* in_sizes, int n_in,
                              void* d_out, int out_size, void* d_ws, size_t ws_size,
                              hipStream_t stream) {
    const float* x       = (const float*)d_in[0];
    const float* ln_w    = (const float*)d_in[1];
    const float* ln_b    = (const float*)d_in[2];
    const float* w_in    = (const float*)d_in[3];
    const float* conv_w  = (const float*)d_in[4];
    const float* conv_b  = (const float*)d_in[5];
    const float* w_xproj = (const float*)d_in[6];
    const float* w_dt    = (const float*)d_in[7];
    const float* b_dt    = (const float*)d_in[8];
    const float* a_log   = (const float*)d_in[9];
    const float* d_skip  = (const float*)d_in[10];
    const float* w_out   = (const float*)d_in[11];
    float* out = (float*)d_out;

    float* ws = (float*)d_ws;
    unsigned short* xn_b    = (unsigned short*)(ws);
    unsigned short* xz_b    = (unsigned short*)(ws + 1048576);
    unsigned short* u_b     = (unsigned short*)(ws + 5242880);
    float* xdbl  = ws + 7340032;
    float* hpart = ws + 9633792;
    float* Aprod = ws + 13828096;
    float* hinit = ws + 18022400;
    unsigned short* y_b     = (unsigned short*)(ws + 22216704);
    unsigned short* w_in_b  = (unsigned short*)(ws + 24313856);
    unsigned short* w_out_b = (unsigned short*)(ws + 26411008);
    unsigned short* w_dt_b  = (unsigned short*)(ws + 27459584);
    float* xpart = ws + 9633792;    // 32x196608, aliases hpart/Aprod (dead until scan)
    float* opart = ws + 1048576;    // aliases xz_b..xdbl (dead after part2)

    // 0. weight converts + LayerNorm, one launch
    setup_kernel<<<8320, 256, 0, stream>>>(w_in, w_in_b, w_out, w_out_b, w_dt, w_dt_b,
                                           x, ln_w, ln_b, xn_b);
    // 1. xz = xn @ w_in^T  (2048 x 4096 x 1024)  MFMA 64x128 -> bf16
    gemm_bf16_nt<<<dim3(32, 32, 1), 256, 0, stream>>>(xn_b, 1024, w_in_b, 1024, 1024,
                                                      nullptr, xz_b, 4096, 3, 0);
    // 2+3. fused conv+silu -> u (side output) + x_dbl split-K partials (32 slices)
    xproj_splitk<<<dim3(32, 32), 256, 0, stream>>>(xz_b, conv_w, conv_b, w_xproj,
                                                   u_b, xpart);
    xproj_reduce<<<768, 256, 0, stream>>>(xpart, xdbl);
    // 4+5. chunked selective scan (LC=16, 64 chunks), 2 thr/channel, dt fused,
    //      B/C staged in LDS
    scan_part1<<<2048, 256, 0, stream>>>(u_b, xdbl, w_dt_b, b_dt, a_log, hpart, Aprod);
    scan_combine<<<256, 256, 0, stream>>>(hpart, Aprod, hinit);
    scan_part2<<<2048, 256, 0, stream>>>(u_b, xdbl, w_dt_b, b_dt, xz_b, a_log,
                                         d_skip, hinit, y_b);
    // 6. out-proj split-K x4 (fp32 partials) + reduce(+residual)
    gemm_bf16_nt<<<dim3(8, 32, 4), 256, 0, stream>>>(y_b, 2048, w_out_b, 2048, 512,
                                                     opart, nullptr, 1024, 0, 2097152);
    out_reduce<<<2048, 256, 0, stream>>>(opart, x, out);
}

// Round 10
// 263.895 us; speedup vs baseline: 1.0934x; 1.0386x over previous
//
#include <hip/hip_runtime.h>
#include <hip/hip_bf16.h>

// MambaBlock: B=2, L=1024, dim=1024, d_inner=2048, DT_RANK=64, D_STATE=16
// Inputs fp32, output fp32. Intermediates xz/u/y bf16; scan state fp32.
// MFMA GEMMs: 64x128 tile, BK=32, 3-buf 2-ahead prefetch, counted vmcnt(3),
// XCD-aware block swizzle. conv+SiLU fused into xproj_splitk (32 K-slices).
// dt-GEMM fused into scan as a per-block 16x128 mini-MFMA (dtl in LDS).
// Scan: 2 threads/channel (8 states each), LC=16, NCHUNK=64 (8 blocks/CU),
// B/C chunk rows staged in LDS; inner-loop exp via NATIVE __expf (v_exp_f32)
// -- round 8/9 used exp2f which lowers to the ~25-inst precise libm poly
// and quadrupled scan VALU work.  9 dispatches total.
//
// ws layout (float units):
//   xn_b  (bf16 2048x1024) : @0          1,048,576
//   xz_b  (bf16 2048x4096) : @1,048,576  4,194,304   } opart (fp32 4x2,097,152)
//   u_b   (bf16 2048x2048) : @5,242,880  2,097,152   }   aliases xz_b..xdbl
//   xdbl  (fp32 2048x96)   : @7,340,032    196,608   }   dead after scan_part2
//   (gap)                  : @7,536,640  2,097,152   }
//   hpart (fp32 64x65536)  : @9,633,792  4,194,304   } xpart 32x196608=6.29M
//   Aprod (fp32 64x65536)  : @13,828,096 4,194,304   }   aliases hpart+Aprod
//   hinit (fp32 64x65536)  : @18,022,400 4,194,304   }   (dead until scan)
//   y_b   (bf16 2048x2048) : @22,216,704 2,097,152
//   w_in_b (bf16)          : @24,313,856 2,097,152
//   w_out_b(bf16)          : @26,411,008 1,048,576
//   w_dt_b (bf16)          : @27,459,584    65,536
// total < 27,590,656 fu = 110 MB (ws = 256 MiB)

#define LC 16
#define NCHUNK 64

typedef short bf16x8 __attribute__((ext_vector_type(8)));
typedef float f32x4  __attribute__((ext_vector_type(4)));

static __device__ __forceinline__ float siluf(float x) { return x / (1.f + __expf(-x)); }
static __device__ __forceinline__ unsigned short f2bf(float f) {
    unsigned int u = __float_as_uint(f);
    unsigned int r = (u + 0x7fffu + ((u >> 16) & 1u)) >> 16;
    return (unsigned short)r;
}
static __device__ __forceinline__ float bfb(unsigned short u) {
    return __uint_as_float(((unsigned int)u) << 16);
}
// async global->LDS, 16 B per lane; LDS dest = wave-uniform base + lane*16
static __device__ __forceinline__ void gload_lds16(const void* g, void* l) {
    __builtin_amdgcn_global_load_lds(
        (const __attribute__((address_space(1))) void*)g,
        (__attribute__((address_space(3))) void*)l, 16, 0, 0);
}

// ---------------- fused setup: weight converts + LayerNorm ----------------
// blocks [0,6272): w_in/w_out/w_dt fp32->bf16;  blocks [6272,8320): LN row m
__global__ __launch_bounds__(256) void setup_kernel(
    const float* __restrict__ w_in,  unsigned short* __restrict__ w_in_b,
    const float* __restrict__ w_out, unsigned short* __restrict__ w_out_b,
    const float* __restrict__ w_dt,  unsigned short* __restrict__ w_dt_b,
    const float* __restrict__ x,
    const float* __restrict__ ln_w,
    const float* __restrict__ ln_b,
    unsigned short* __restrict__ xn)
{
    int bid = blockIdx.x, tid = threadIdx.x;
    if (bid < 6272) {
        int i = bid * 256 + tid;
        const float* in; unsigned short* outp; int j;
        if (i < 1048576)      { in = w_in;  outp = w_in_b;  j = i; }
        else if (i < 1572864) { in = w_out; outp = w_out_b; j = i - 1048576; }
        else if (i < 1605632) { in = w_dt;  outp = w_dt_b;  j = i - 1572864; }
        else return;
        float4 v = reinterpret_cast<const float4*>(in)[j];
        ushort4 o = { f2bf(v.x), f2bf(v.y), f2bf(v.z), f2bf(v.w) };
        reinterpret_cast<ushort4*>(outp)[j] = o;
        return;
    }
    int m = bid - 6272;
    const float4* xr = reinterpret_cast<const float4*>(x) + (size_t)m * 256;
    float4 r = xr[tid];
    float f0 = r.x, f1 = r.y, f2 = r.z, f3 = r.w;
    float s  = f0 + f1 + f2 + f3;
    float s2 = f0*f0 + f1*f1 + f2*f2 + f3*f3;
    #pragma unroll
    for (int off = 32; off > 0; off >>= 1) {
        s  += __shfl_down(s, off);
        s2 += __shfl_down(s2, off);
    }
    __shared__ float red[8];
    if ((tid & 63) == 0) { red[tid >> 6] = s; red[4 + (tid >> 6)] = s2; }
    __syncthreads();
    float st = red[0] + red[1] + red[2] + red[3];
    float qt = red[4] + red[5] + red[6] + red[7];
    float mu   = st * (1.f / 1024.f);
    float var  = qt * (1.f / 1024.f) - mu * mu;
    float rstd = rsqrtf(var + 1e-5f);
    float4 wv = reinterpret_cast<const float4*>(ln_w)[tid];
    float4 bv = reinterpret_cast<const float4*>(ln_b)[tid];
    ushort4 o = { f2bf((f0 - mu) * rstd * wv.x + bv.x),
                  f2bf((f1 - mu) * rstd * wv.y + bv.y),
                  f2bf((f2 - mu) * rstd * wv.z + bv.z),
                  f2bf((f3 - mu) * rstd * wv.w + bv.w) };
    reinterpret_cast<ushort4*>(xn + (size_t)m * 1024)[tid] = o;
}

// ---------------- bf16 MFMA GEMM-NT, 64x128 tile, 3-buf counted-vmcnt ----------
// 4 waves in 2x2 grid over (M=64, N=128); each wave 32x64 (acc[2][4]).
// XCD swizzle: contiguous tile chunk per XCD (grid %8==0 -> bijective).
// ep: 0 = fp32 raw -> C; 3 = raw -> Cb bf16
__global__ __launch_bounds__(256) void gemm_bf16_nt(
    const unsigned short* __restrict__ A, int lda,
    const unsigned short* __restrict__ B, int ldb,
    int Kslice,
    float* __restrict__ C, unsigned short* __restrict__ Cb, int ldc,
    int ep, size_t Cstride)
{
    __shared__ short As[3 * 64 * 32];    // 12 KB
    __shared__ short Bs[3 * 128 * 32];   // 24 KB
    int tid = threadIdx.x;
    int z = blockIdx.z;
    A += (size_t)z * Kslice;
    B += (size_t)z * Kslice;
    C += (size_t)z * Cstride;

    // XCD-aware swizzle over (x,y) tile grid
    int gx = gridDim.x;
    int wg = blockIdx.y * gx + blockIdx.x;
    int nwg = gx * gridDim.y;
    int cpx = nwg >> 3;
    int swz = (wg & 7) * cpx + (wg >> 3);
    int bx = swz % gx, by = swz / gx;

    int m0 = by * 64, n0 = bx * 128;
    int lane = tid & 63, wave = tid >> 6;
    int wm = (wave >> 1) * 32, wn = (wave & 1) * 64;
    int frow = lane & 15, fq = lane >> 4;

    f32x4 acc[2][4] = {};

    int lrow = lane >> 2;
    int scol = (lane & 3) * 8;
    const unsigned short* AgL = A + (size_t)(m0 + wave * 16 + lrow) * lda + scol;
    const unsigned short* BgL = B + (size_t)(n0 + wave * 16 + lrow) * ldb + scol;
    int aoff = (wave * 16) * 32;   // shorts
    int boff = (wave * 16) * 32;

    // prologue: stage buffers 0 and 1 (6 loads in flight per wave)
    #pragma unroll
    for (int p = 0; p < 2; ++p) {
        int nk = p * 32;
        gload_lds16(AgL + nk,                    As + p * 2048 + aoff);
        gload_lds16(BgL + nk,                    Bs + p * 4096 + boff);
        gload_lds16(BgL + (size_t)64 * ldb + nk, Bs + p * 4096 + boff + 64 * 32);
    }

    int cur = 0;
    for (int k0 = 0; k0 < Kslice; k0 += 32) {
        if (k0 + 32 < Kslice) {
            asm volatile("s_waitcnt vmcnt(3) lgkmcnt(0)" ::: "memory");
        } else {
            asm volatile("s_waitcnt vmcnt(0) lgkmcnt(0)" ::: "memory");
        }
        __builtin_amdgcn_s_barrier();
        int nk = k0 + 64;
        if (nk < Kslice) {
            int stg = cur - 1; if (stg < 0) stg = 2;   // (cur+2)%3
            gload_lds16(AgL + nk,                    As + stg * 2048 + aoff);
            gload_lds16(BgL + nk,                    Bs + stg * 4096 + boff);
            gload_lds16(BgL + (size_t)64 * ldb + nk, Bs + stg * 4096 + boff + 64 * 32);
        }
        const short* Ac = As + cur * 2048;
        const short* Bc = Bs + cur * 4096;
        bf16x8 af[2], bfr[4];
        #pragma unroll
        for (int i = 0; i < 2; ++i)
            af[i] = *reinterpret_cast<const bf16x8*>(Ac + (wm + i * 16 + frow) * 32 + fq * 8);
        #pragma unroll
        for (int j = 0; j < 4; ++j)
            bfr[j] = *reinterpret_cast<const bf16x8*>(Bc + (wn + j * 16 + frow) * 32 + fq * 8);
        #pragma unroll
        for (int i = 0; i < 2; ++i)
            #pragma unroll
            for (int j = 0; j < 4; ++j)
                acc[i][j] = __builtin_amdgcn_mfma_f32_16x16x32_bf16(af[i], bfr[j], acc[i][j], 0, 0, 0);
        cur = (cur == 2) ? 0 : cur + 1;
    }

    int cn = lane & 15, rq = (lane >> 4) * 4;
    #pragma unroll
    for (int i = 0; i < 2; ++i) {
        #pragma unroll
        for (int j = 0; j < 4; ++j) {
            #pragma unroll
            for (int r = 0; r < 4; ++r) {
                int row = m0 + wm + i * 16 + rq + r;
                int col = n0 + wn + j * 16 + cn;
                float v = acc[i][j][r];
                if (ep == 0) {
                    C[(size_t)row * ldc + col] = v;
                } else {
                    Cb[(size_t)row * ldc + col] = f2bf(v);
                }
            }
        }
    }
}

// ---------------- out = x + sum_z part[z] ----------------
__global__ __launch_bounds__(256) void out_reduce(
    const float* __restrict__ part, const float* __restrict__ x,
    float* __restrict__ out)
{
    int i = blockIdx.x * 256 + threadIdx.x;
    float4 s = reinterpret_cast<const float4*>(x)[i];
    #pragma unroll
    for (int z = 0; z < 4; ++z) {
        float4 p = reinterpret_cast<const float4*>(part + (size_t)z * 2097152)[i];
        s.x += p.x; s.y += p.y; s.z += p.z; s.w += p.w;
    }
    reinterpret_cast<float4*>(out)[i] = s;
}

// ---------------- xproj split-K with fused depthwise conv + SiLU ----------------
// 32 K-slices of 64 (grid 32x32 = 1024 blocks = 4/CU).
__global__ __launch_bounds__(256) void xproj_splitk(
    const unsigned short* __restrict__ xz,
    const float* __restrict__ cw,
    const float* __restrict__ cb,
    const float* __restrict__ B,
    unsigned short* __restrict__ u,
    float* __restrict__ part)
{
    __shared__ float As[16][68];
    __shared__ float Bs[16][100];
    int tid = threadIdx.x;
    int m0 = blockIdx.x * 64;
    int k0 = blockIdx.y * 64;
    int tx = tid & 15;
    int ty = tid >> 4;
    float acc[4][6] = {};
    int arow = tid >> 2, akg = (tid & 3) << 2;
    int brow1 = (256 + tid) >> 2, bkg1 = ((256 + tid) & 3) << 2;
    int m = m0 + arow;
    int l = m & 1023;

    for (int ks = 0; ks < 64; ks += 16) {
        int e0 = k0 + ks + akg;
        // --- fused conv+silu for 4 consecutive e at row m ---
        float xv[4][4];   // [kk][j]
        #pragma unroll
        for (int kk = 0; kk < 4; ++kk) {
            ushort4 t = make_ushort4(0, 0, 0, 0);
            if (l - 3 + kk >= 0)
                t = *reinterpret_cast<const ushort4*>(xz + (size_t)(m - 3 + kk) * 4096 + e0);
            xv[kk][0] = bfb(t.x); xv[kk][1] = bfb(t.y);
            xv[kk][2] = bfb(t.z); xv[kk][3] = bfb(t.w);
        }
        float4 cbv = *reinterpret_cast<const float4*>(cb + e0);
        float cbs[4] = { cbv.x, cbv.y, cbv.z, cbv.w };
        float res[4];
        #pragma unroll
        for (int j = 0; j < 4; ++j) {
            float4 w = *reinterpret_cast<const float4*>(cw + (size_t)(e0 + j) * 4);
            float a = cbs[j];
            a = fmaf(w.x, xv[0][j], a);
            a = fmaf(w.y, xv[1][j], a);
            a = fmaf(w.z, xv[2][j], a);
            a = fmaf(w.w, xv[3][j], a);
            res[j] = siluf(a);
        }
        ushort4 uo = { f2bf(res[0]), f2bf(res[1]), f2bf(res[2]), f2bf(res[3]) };
        *reinterpret_cast<ushort4*>(u + (size_t)m * 2048 + e0) = uo;

        // --- B (w_xproj) loads ---
        float4 bv0 = make_float4(0.f, 0.f, 0.f, 0.f), bv1 = bv0;
        if (arow < 96)  bv0 = *reinterpret_cast<const float4*>(B + (size_t)arow * 2048 + k0 + ks + akg);
        if (brow1 < 96) bv1 = *reinterpret_cast<const float4*>(B + (size_t)brow1 * 2048 + k0 + ks + bkg1);
        __syncthreads();
        As[akg + 0][arow] = res[0]; As[akg + 1][arow] = res[1];
        As[akg + 2][arow] = res[2]; As[akg + 3][arow] = res[3];
        if (arow < 96) {
            Bs[akg + 0][arow] = bv0.x; Bs[akg + 1][arow] = bv0.y;
            Bs[akg + 2][arow] = bv0.z; Bs[akg + 3][arow] = bv0.w;
        }
        if (brow1 < 96) {
            Bs[bkg1 + 0][brow1] = bv1.x; Bs[bkg1 + 1][brow1] = bv1.y;
            Bs[bkg1 + 2][brow1] = bv1.z; Bs[bkg1 + 3][brow1] = bv1.w;
        }
        __syncthreads();
        #pragma unroll
        for (int k = 0; k < 16; ++k) {
            float aa[4], bb[6];
            #pragma unroll
            for (int i = 0; i < 4; ++i) aa[i] = As[k][ty * 4 + i];
            #pragma unroll
            for (int j = 0; j < 6; ++j) bb[j] = Bs[k][tx * 6 + j];
            #pragma unroll
            for (int i = 0; i < 4; ++i)
                #pragma unroll
                for (int j = 0; j < 6; ++j)
                    acc[i][j] = fmaf(aa[i], bb[j], acc[i][j]);
        }
    }
    float* p = part + (size_t)blockIdx.y * 196608;
    #pragma unroll
    for (int i = 0; i < 4; ++i)
        #pragma unroll
        for (int j = 0; j < 6; ++j)
            p[(size_t)(m0 + ty * 4 + i) * 96 + tx * 6 + j] = acc[i][j];
}

// reduce 32 partials -> xdbl fp32
__global__ __launch_bounds__(256) void xproj_reduce(
    const float* __restrict__ part, float* __restrict__ xdbl)
{
    int i = blockIdx.x * 256 + threadIdx.x;   // 196608
    float s = 0.f;
    #pragma unroll
    for (int sd = 0; sd < 32; ++sd) s += part[(size_t)sd * 196608 + i];
    xdbl[i] = s;
}

// ---- fused dt tile: dtl[16 l][128 e] = softplus(bf16(xdbl[:, :64]) @ w_dt^T + b_dt)
// 4 MFMAs per wave (2 e-frags x 2 k); bf16-rounded result in LDS.
static __device__ __forceinline__ void dt_tile16(
    const float* __restrict__ xdbl, const unsigned short* __restrict__ w_dt_b,
    const float* __restrict__ b_dt, size_t rbase, int et,
    int lane, int wave, float dtl[LC][128])
{
    int frow = lane & 15, fq = lane >> 4;
    bf16x8 af[2];
    #pragma unroll
    for (int kk = 0; kk < 2; ++kk) {
        const float* ap = xdbl + (rbase + frow) * 96 + kk * 32 + fq * 8;
        float4 a0 = *reinterpret_cast<const float4*>(ap);
        float4 a1 = *reinterpret_cast<const float4*>(ap + 4);
        bf16x8 t;
        t[0] = (short)f2bf(a0.x); t[1] = (short)f2bf(a0.y);
        t[2] = (short)f2bf(a0.z); t[3] = (short)f2bf(a0.w);
        t[4] = (short)f2bf(a1.x); t[5] = (short)f2bf(a1.y);
        t[6] = (short)f2bf(a1.z); t[7] = (short)f2bf(a1.w);
        af[kk] = t;
    }
    f32x4 dacc[2] = {};
    #pragma unroll
    for (int j = 0; j < 2; ++j)
        #pragma unroll
        for (int kk = 0; kk < 2; ++kk) {
            int row_e = et * 128 + wave * 32 + j * 16 + frow;
            bf16x8 bfr = *reinterpret_cast<const bf16x8*>(
                w_dt_b + (size_t)row_e * 64 + kk * 32 + fq * 8);
            dacc[j] = __builtin_amdgcn_mfma_f32_16x16x32_bf16(af[kk], bfr, dacc[j], 0, 0, 0);
        }
    int cn = lane & 15, rq = (lane >> 4) * 4;
    #pragma unroll
    for (int j = 0; j < 2; ++j)
        #pragma unroll
        for (int r = 0; r < 4; ++r) {
            int row = rq + r;                      // 0..15 (l)
            int col = wave * 32 + j * 16 + cn;     // 0..127 (e)
            float v = dacc[j][r] + b_dt[et * 128 + col];
            v = (v > 20.f) ? v : log1pf(__expf(v));
            dtl[row][col] = bfb(f2bf(v));
        }
}

// ---------------- Chunked selective scan: 2 threads/channel, 8 states ----------
// grid 2048 = (b:2) x (et:16) x (c:64); 256 threads = 128 ch x 2 ngroups.
// 8 blocks/CU. B (and C) chunk rows staged in LDS; inner loop: 1 VMEM + LDS.
// d = __expf(dt * A)  (native v_exp_f32 -- NOT libm exp2f).
__global__ __launch_bounds__(256) void scan_part1(
    const unsigned short* __restrict__ u,
    const float* __restrict__ xdbl,
    const unsigned short* __restrict__ w_dt_b,
    const float* __restrict__ b_dt,
    const float* __restrict__ a_log,
    float* __restrict__ hpart,
    float* __restrict__ Aprod)
{
    __shared__ float dtl[LC][128];
    __shared__ float Bl[LC][16];
    int tid = threadIdx.x;
    int lane = tid & 63, wave = tid >> 6;
    int bid = blockIdx.x;
    int c = bid & 63, et = (bid >> 6) & 15, b = bid >> 10;
    int ch = tid >> 1, ng = tid & 1;
    int e = et * 128 + ch;
    size_t rbase = (size_t)b * 1024 + c * LC;

    // stage B rows: 16 l x 16 states, one float per thread
    Bl[tid >> 4][tid & 15] = xdbl[(rbase + (tid >> 4)) * 96 + 64 + (tid & 15)];

    dt_tile16(xdbl, w_dt_b, b_dt, rbase, et, lane, wave, dtl);

    float A[8];
    {
        float4 a0 = *reinterpret_cast<const float4*>(a_log + (size_t)e * 16 + ng * 8);
        float4 a1 = *reinterpret_cast<const float4*>(a_log + (size_t)e * 16 + ng * 8 + 4);
        A[0] = -__expf(a0.x); A[1] = -__expf(a0.y);
        A[2] = -__expf(a0.z); A[3] = -__expf(a0.w);
        A[4] = -__expf(a1.x); A[5] = -__expf(a1.y);
        A[6] = -__expf(a1.z); A[7] = -__expf(a1.w);
    }
    float h[8], P[8];
    #pragma unroll
    for (int n = 0; n < 8; ++n) { h[n] = 0.f; P[n] = 1.f; }

    const unsigned short* u_p = u + rbase * 2048 + e;
    __syncthreads();
    #pragma unroll 8
    for (int l = 0; l < LC; ++l) {
        float dtv = dtl[l][ch];
        float u_c = bfb(u_p[(size_t)l * 2048]);
        float4 b0 = *reinterpret_cast<const float4*>(&Bl[l][ng * 8]);
        float4 b1 = *reinterpret_cast<const float4*>(&Bl[l][ng * 8 + 4]);
        float Bv[8] = { b0.x, b0.y, b0.z, b0.w, b1.x, b1.y, b1.z, b1.w };
        float du = dtv * u_c;
        #pragma unroll
        for (int n = 0; n < 8; ++n) {
            float d = __expf(dtv * A[n]);
            h[n] = fmaf(d, h[n], du * Bv[n]);
            P[n] *= d;
        }
    }
    size_t oidx = (size_t)c * 65536 + ((size_t)b * 2048 + e) * 16 + ng * 8;
    *reinterpret_cast<float4*>(hpart + oidx)     = make_float4(h[0], h[1], h[2], h[3]);
    *reinterpret_cast<float4*>(hpart + oidx + 4) = make_float4(h[4], h[5], h[6], h[7]);
    *reinterpret_cast<float4*>(Aprod + oidx)     = make_float4(P[0], P[1], P[2], P[3]);
    *reinterpret_cast<float4*>(Aprod + oidx + 4) = make_float4(P[4], P[5], P[6], P[7]);
}

// 65536 scalar chains, 1 float/thread -> 256 blocks (all CUs busy)
__global__ __launch_bounds__(256) void scan_combine(
    const float* __restrict__ hpart,
    const float* __restrict__ Aprod,
    float* __restrict__ hinit)
{
    int t = blockIdx.x * 256 + threadIdx.x;   // 65536 threads x 1 float
    float h = 0.f;
    #pragma unroll 8
    for (int c = 0; c < NCHUNK; ++c) {
        hinit[(size_t)c * 65536 + t] = h;
        float P  = Aprod[(size_t)c * 65536 + t];
        float hp = hpart[(size_t)c * 65536 + t];
        h = fmaf(P, h, hp);
    }
}

__global__ __launch_bounds__(256) void scan_part2(
    const unsigned short* __restrict__ u,
    const float* __restrict__ xdbl,
    const unsigned short* __restrict__ w_dt_b,
    const float* __restrict__ b_dt,
    const unsigned short* __restrict__ xz,
    const float* __restrict__ a_log,
    const float* __restrict__ d_skip,
    const float* __restrict__ hinit,
    unsigned short* __restrict__ y)
{
    __shared__ float dtl[LC][128];
    __shared__ float BCl[LC][32];
    int tid = threadIdx.x;
    int lane = tid & 63, wave = tid >> 6;
    int bid = blockIdx.x;
    int c = bid & 63, et = (bid >> 6) & 15, b = bid >> 10;
    int ch = tid >> 1, ng = tid & 1;
    int e = et * 128 + ch;
    size_t rbase = (size_t)b * 1024 + c * LC;

    // stage B+C rows: 16 l x 32 floats, two floats per thread
    #pragma unroll
    for (int s = 0; s < 2; ++s) {
        int idx = s * 256 + tid;   // < 512
        BCl[idx >> 5][idx & 31] = xdbl[(rbase + (idx >> 5)) * 96 + 64 + (idx & 31)];
    }

    dt_tile16(xdbl, w_dt_b, b_dt, rbase, et, lane, wave, dtl);

    float A[8];
    {
        float4 a0 = *reinterpret_cast<const float4*>(a_log + (size_t)e * 16 + ng * 8);
        float4 a1 = *reinterpret_cast<const float4*>(a_log + (size_t)e * 16 + ng * 8 + 4);
        A[0] = -__expf(a0.x); A[1] = -__expf(a0.y);
        A[2] = -__expf(a0.z); A[3] = -__expf(a0.w);
        A[4] = -__expf(a1.x); A[5] = -__expf(a1.y);
        A[6] = -__expf(a1.z); A[7] = -__expf(a1.w);
    }
    float dsk = d_skip[e];
    float h[8];
    size_t oidx = (size_t)c * 65536 + ((size_t)b * 2048 + e) * 16 + ng * 8;
    {
        float4 h0 = *reinterpret_cast<const float4*>(hinit + oidx);
        float4 h1 = *reinterpret_cast<const float4*>(hinit + oidx + 4);
        h[0] = h0.x; h[1] = h0.y; h[2] = h0.z; h[3] = h0.w;
        h[4] = h1.x; h[5] = h1.y; h[6] = h1.z; h[7] = h1.w;
    }

    const unsigned short* u_p = u + rbase * 2048 + e;
    const unsigned short* z_p = xz + rbase * 4096 + 2048 + e;
    unsigned short* y_p = y + rbase * 2048 + e;
    __syncthreads();
    #pragma unroll 8
    for (int l = 0; l < LC; ++l) {
        float dtv = dtl[l][ch];
        float u_c = bfb(u_p[(size_t)l * 2048]);
        float4 b0 = *reinterpret_cast<const float4*>(&BCl[l][ng * 8]);
        float4 b1 = *reinterpret_cast<const float4*>(&BCl[l][ng * 8 + 4]);
        float4 c0 = *reinterpret_cast<const float4*>(&BCl[l][16 + ng * 8]);
        float4 c1 = *reinterpret_cast<const float4*>(&BCl[l][16 + ng * 8 + 4]);
        float Bv[8] = { b0.x, b0.y, b0.z, b0.w, b1.x, b1.y, b1.z, b1.w };
        float Cv[8] = { c0.x, c0.y, c0.z, c0.w, c1.x, c1.y, c1.z, c1.w };
        float du = dtv * u_c;
        float p = 0.f;
        #pragma unroll
        for (int n = 0; n < 8; ++n) {
            float d = __expf(dtv * A[n]);
            h[n] = fmaf(d, h[n], du * Bv[n]);
            p = fmaf(h[n], Cv[n], p);
        }
        p += __shfl_xor(p, 1);
        if (ng == 0) {
            float zv = bfb(z_p[(size_t)l * 4096]);
            y_p[(size_t)l * 2048] = f2bf((p + u_c * dsk) * siluf(zv));
        }
    }
}

extern "C" void kernel_launch(void* const* d_in, const int* in_sizes, int n_in,
                              void* d_out, int out_size, void* d_ws, size_t ws_size,
                              hipStream_t stream) {
    const float* x       = (const float*)d_in[0];
    const float* ln_w    = (const float*)d_in[1];
    const float* ln_b    = (const float*)d_in[2];
    const float* w_in    = (const float*)d_in[3];
    const float* conv_w  = (const float*)d_in[4];
    const float* conv_b  = (const float*)d_in[5];
    const float* w_xproj = (const float*)d_in[6];
    const float* w_dt    = (const float*)d_in[7];
    const float* b_dt    = (const float*)d_in[8];
    const float* a_log   = (const float*)d_in[9];
    const float* d_skip  = (const float*)d_in[10];
    const float* w_out   = (const float*)d_in[11];
    float* out = (float*)d_out;

    float* ws = (float*)d_ws;
    unsigned short* xn_b    = (unsigned short*)(ws);
    unsigned short* xz_b    = (unsigned short*)(ws + 1048576);
    unsigned short* u_b     = (unsigned short*)(ws + 5242880);
    float* xdbl  = ws + 7340032;
    float* hpart = ws + 9633792;
    float* Aprod = ws + 13828096;
    float* hinit = ws + 18022400;
    unsigned short* y_b     = (unsigned short*)(ws + 22216704);
    unsigned short* w_in_b  = (unsigned short*)(ws + 24313856);
    unsigned short* w_out_b = (unsigned short*)(ws + 26411008);
    unsigned short* w_dt_b  = (unsigned short*)(ws + 27459584);
    float* xpart = ws + 9633792;    // 32x196608, aliases hpart/Aprod (dead until scan)
    float* opart = ws + 1048576;    // aliases xz_b..xdbl (dead after part2)

    // 0. weight converts + LayerNorm, one launch
    setup_kernel<<<8320, 256, 0, stream>>>(w_in, w_in_b, w_out, w_out_b, w_dt, w_dt_b,
                                           x, ln_w, ln_b, xn_b);
    // 1. xz = xn @ w_in^T  (2048 x 4096 x 1024)  MFMA 64x128 -> bf16
    gemm_bf16_nt<<<dim3(32, 32, 1), 256, 0, stream>>>(xn_b, 1024, w_in_b, 1024, 1024,
                                                      nullptr, xz_b, 4096, 3, 0);
    // 2+3. fused conv+silu -> u (side output) + x_dbl split-K partials (32 slices)
    xproj_splitk<<<dim3(32, 32), 256, 0, stream>>>(xz_b, conv_w, conv_b, w_xproj,
                                                   u_b, xpart);
    xproj_reduce<<<768, 256, 0, stream>>>(xpart, xdbl);
    // 4+5. chunked selective scan (LC=16, 64 chunks), 2 thr/channel, dt fused,
    //      B/C staged in LDS, native __expf
    scan_part1<<<2048, 256, 0, stream>>>(u_b, xdbl, w_dt_b, b_dt, a_log, hpart, Aprod);
    scan_combine<<<256, 256, 0, stream>>>(hpart, Aprod, hinit);
    scan_part2<<<2048, 256, 0, stream>>>(u_b, xdbl, w_dt_b, b_dt, xz_b, a_log,
                                         d_skip, hinit, y_b);
    // 6. out-proj split-K x4 (fp32 partials) + reduce(+residual)
    gemm_bf16_nt<<<dim3(8, 32, 4), 256, 0, stream>>>(y_b, 2048, w_out_b, 2048, 512,
                                                     opart, nullptr, 1024, 0, 2097152);
    out_reduce<<<2048, 256, 0, stream>>>(opart, x, out);
}

// Round 12
// 242.657 us; speedup vs baseline: 1.1890x; 1.0875x over previous
//
#include <hip/hip_runtime.h>
#include <hip/hip_bf16.h>

// MambaBlock: B=2, L=1024, dim=1024, d_inner=2048, DT_RANK=64, D_STATE=16
// Inputs fp32, output fp32. Intermediates xz/u/y bf16; scan state fp32.
// MFMA GEMMs: 64x128 tile, BK=32, 3-buf 2-ahead prefetch, counted vmcnt(3),
// XCD-aware block swizzle. conv+SiLU fused into xproj_splitk (32 K-slices).
// dt-GEMM fused into scan as a per-block 16x128 mini-MFMA (dtl in LDS).
// Scan: 2 threads/channel (8 states each), LC=16, NCHUNK=64 (8 blocks/CU),
// B/C chunk rows staged in LDS, u preloaded into regs (latency batch),
// part1 P via exp(A*S) cumsum identity, native __expf/__logf only.
// 9 dispatches total.  (Resubmit of round-11 kernel; container failure.)
//
// ws layout (float units):
//   xn_b  (bf16 2048x1024) : @0          1,048,576
//   xz_b  (bf16 2048x4096) : @1,048,576  4,194,304   } opart (fp32 4x2,097,152)
//   u_b   (bf16 2048x2048) : @5,242,880  2,097,152   }   aliases xz_b..xdbl
//   xdbl  (fp32 2048x96)   : @7,340,032    196,608   }   dead after scan_part2
//   (gap)                  : @7,536,640  2,097,152   }
//   hpart (fp32 64x65536)  : @9,633,792  4,194,304   } xpart 32x196608=6.29M
//   Aprod (fp32 64x65536)  : @13,828,096 4,194,304   }   aliases hpart+Aprod
//   hinit (fp32 64x65536)  : @18,022,400 4,194,304   }   (dead until scan)
//   y_b   (bf16 2048x2048) : @22,216,704 2,097,152
//   w_in_b (bf16)          : @24,313,856 2,097,152
//   w_out_b(bf16)          : @26,411,008 1,048,576
//   w_dt_b (bf16)          : @27,459,584    65,536
// total < 27,590,656 fu = 110 MB (ws = 256 MiB)

#define LC 16
#define NCHUNK 64

typedef short bf16x8 __attribute__((ext_vector_type(8)));
typedef float f32x4  __attribute__((ext_vector_type(4)));

static __device__ __forceinline__ float siluf(float x) { return x / (1.f + __expf(-x)); }
static __device__ __forceinline__ unsigned short f2bf(float f) {
    unsigned int u = __float_as_uint(f);
    unsigned int r = (u + 0x7fffu + ((u >> 16) & 1u)) >> 16;
    return (unsigned short)r;
}
static __device__ __forceinline__ float bfb(unsigned short u) {
    return __uint_as_float(((unsigned int)u) << 16);
}
// async global->LDS, 16 B per lane; LDS dest = wave-uniform base + lane*16
static __device__ __forceinline__ void gload_lds16(const void* g, void* l) {
    __builtin_amdgcn_global_load_lds(
        (const __attribute__((address_space(1))) void*)g,
        (__attribute__((address_space(3))) void*)l, 16, 0, 0);
}

// ---------------- fused setup: weight converts + LayerNorm ----------------
// blocks [0,6272): w_in/w_out/w_dt fp32->bf16;  blocks [6272,8320): LN row m
__global__ __launch_bounds__(256) void setup_kernel(
    const float* __restrict__ w_in,  unsigned short* __restrict__ w_in_b,
    const float* __restrict__ w_out, unsigned short* __restrict__ w_out_b,
    const float* __restrict__ w_dt,  unsigned short* __restrict__ w_dt_b,
    const float* __restrict__ x,
    const float* __restrict__ ln_w,
    const float* __restrict__ ln_b,
    unsigned short* __restrict__ xn)
{
    int bid = blockIdx.x, tid = threadIdx.x;
    if (bid < 6272) {
        int i = bid * 256 + tid;
        const float* in; unsigned short* outp; int j;
        if (i < 1048576)      { in = w_in;  outp = w_in_b;  j = i; }
        else if (i < 1572864) { in = w_out; outp = w_out_b; j = i - 1048576; }
        else if (i < 1605632) { in = w_dt;  outp = w_dt_b;  j = i - 1572864; }
        else return;
        float4 v = reinterpret_cast<const float4*>(in)[j];
        ushort4 o = { f2bf(v.x), f2bf(v.y), f2bf(v.z), f2bf(v.w) };
        reinterpret_cast<ushort4*>(outp)[j] = o;
        return;
    }
    int m = bid - 6272;
    const float4* xr = reinterpret_cast<const float4*>(x) + (size_t)m * 256;
    float4 r = xr[tid];
    float f0 = r.x, f1 = r.y, f2 = r.z, f3 = r.w;
    float s  = f0 + f1 + f2 + f3;
    float s2 = f0*f0 + f1*f1 + f2*f2 + f3*f3;
    #pragma unroll
    for (int off = 32; off > 0; off >>= 1) {
        s  += __shfl_down(s, off);
        s2 += __shfl_down(s2, off);
    }
    __shared__ float red[8];
    if ((tid & 63) == 0) { red[tid >> 6] = s; red[4 + (tid >> 6)] = s2; }
    __syncthreads();
    float st = red[0] + red[1] + red[2] + red[3];
    float qt = red[4] + red[5] + red[6] + red[7];
    float mu   = st * (1.f / 1024.f);
    float var  = qt * (1.f / 1024.f) - mu * mu;
    float rstd = rsqrtf(var + 1e-5f);
    float4 wv = reinterpret_cast<const float4*>(ln_w)[tid];
    float4 bv = reinterpret_cast<const float4*>(ln_b)[tid];
    ushort4 o = { f2bf((f0 - mu) * rstd * wv.x + bv.x),
                  f2bf((f1 - mu) * rstd * wv.y + bv.y),
                  f2bf((f2 - mu) * rstd * wv.z + bv.z),
                  f2bf((f3 - mu) * rstd * wv.w + bv.w) };
    reinterpret_cast<ushort4*>(xn + (size_t)m * 1024)[tid] = o;
}

// ---------------- bf16 MFMA GEMM-NT, 64x128 tile, 3-buf counted-vmcnt ----------
// 4 waves in 2x2 grid over (M=64, N=128); each wave 32x64 (acc[2][4]).
// XCD swizzle: contiguous tile chunk per XCD (grid %8==0 -> bijective).
// ep: 0 = fp32 raw -> C; 3 = raw -> Cb bf16
__global__ __launch_bounds__(256) void gemm_bf16_nt(
    const unsigned short* __restrict__ A, int lda,
    const unsigned short* __restrict__ B, int ldb,
    int Kslice,
    float* __restrict__ C, unsigned short* __restrict__ Cb, int ldc,
    int ep, size_t Cstride)
{
    __shared__ short As[3 * 64 * 32];    // 12 KB
    __shared__ short Bs[3 * 128 * 32];   // 24 KB
    int tid = threadIdx.x;
    int z = blockIdx.z;
    A += (size_t)z * Kslice;
    B += (size_t)z * Kslice;
    C += (size_t)z * Cstride;

    // XCD-aware swizzle over (x,y) tile grid
    int gx = gridDim.x;
    int wg = blockIdx.y * gx + blockIdx.x;
    int nwg = gx * gridDim.y;
    int cpx = nwg >> 3;
    int swz = (wg & 7) * cpx + (wg >> 3);
    int bx = swz % gx, by = swz / gx;

    int m0 = by * 64, n0 = bx * 128;
    int lane = tid & 63, wave = tid >> 6;
    int wm = (wave >> 1) * 32, wn = (wave & 1) * 64;
    int frow = lane & 15, fq = lane >> 4;

    f32x4 acc[2][4] = {};

    int lrow = lane >> 2;
    int scol = (lane & 3) * 8;
    const unsigned short* AgL = A + (size_t)(m0 + wave * 16 + lrow) * lda + scol;
    const unsigned short* BgL = B + (size_t)(n0 + wave * 16 + lrow) * ldb + scol;
    int aoff = (wave * 16) * 32;   // shorts
    int boff = (wave * 16) * 32;

    // prologue: stage buffers 0 and 1 (6 loads in flight per wave)
    #pragma unroll
    for (int p = 0; p < 2; ++p) {
        int nk = p * 32;
        gload_lds16(AgL + nk,                    As + p * 2048 + aoff);
        gload_lds16(BgL + nk,                    Bs + p * 4096 + boff);
        gload_lds16(BgL + (size_t)64 * ldb + nk, Bs + p * 4096 + boff + 64 * 32);
    }

    int cur = 0;
    for (int k0 = 0; k0 < Kslice; k0 += 32) {
        if (k0 + 32 < Kslice) {
            asm volatile("s_waitcnt vmcnt(3) lgkmcnt(0)" ::: "memory");
        } else {
            asm volatile("s_waitcnt vmcnt(0) lgkmcnt(0)" ::: "memory");
        }
        __builtin_amdgcn_s_barrier();
        int nk = k0 + 64;
        if (nk < Kslice) {
            int stg = cur - 1; if (stg < 0) stg = 2;   // (cur+2)%3
            gload_lds16(AgL + nk,                    As + stg * 2048 + aoff);
            gload_lds16(BgL + nk,                    Bs + stg * 4096 + boff);
            gload_lds16(BgL + (size_t)64 * ldb + nk, Bs + stg * 4096 + boff + 64 * 32);
        }
        const short* Ac = As + cur * 2048;
        const short* Bc = Bs + cur * 4096;
        bf16x8 af[2], bfr[4];
        #pragma unroll
        for (int i = 0; i < 2; ++i)
            af[i] = *reinterpret_cast<const bf16x8*>(Ac + (wm + i * 16 + frow) * 32 + fq * 8);
        #pragma unroll
        for (int j = 0; j < 4; ++j)
            bfr[j] = *reinterpret_cast<const bf16x8*>(Bc + (wn + j * 16 + frow) * 32 + fq * 8);
        #pragma unroll
        for (int i = 0; i < 2; ++i)
            #pragma unroll
            for (int j = 0; j < 4; ++j)
                acc[i][j] = __builtin_amdgcn_mfma_f32_16x16x32_bf16(af[i], bfr[j], acc[i][j], 0, 0, 0);
        cur = (cur == 2) ? 0 : cur + 1;
    }

    int cn = lane & 15, rq = (lane >> 4) * 4;
    #pragma unroll
    for (int i = 0; i < 2; ++i) {
        #pragma unroll
        for (int j = 0; j < 4; ++j) {
            #pragma unroll
            for (int r = 0; r < 4; ++r) {
                int row = m0 + wm + i * 16 + rq + r;
                int col = n0 + wn + j * 16 + cn;
                float v = acc[i][j][r];
                if (ep == 0) {
                    C[(size_t)row * ldc + col] = v;
                } else {
                    Cb[(size_t)row * ldc + col] = f2bf(v);
                }
            }
        }
    }
}

// ---------------- out = x + sum_z part[z] ----------------
__global__ __launch_bounds__(256) void out_reduce(
    const float* __restrict__ part, const float* __restrict__ x,
    float* __restrict__ out)
{
    int i = blockIdx.x * 256 + threadIdx.x;
    float4 s = reinterpret_cast<const float4*>(x)[i];
    #pragma unroll
    for (int z = 0; z < 4; ++z) {
        float4 p = reinterpret_cast<const float4*>(part + (size_t)z * 2097152)[i];
        s.x += p.x; s.y += p.y; s.z += p.z; s.w += p.w;
    }
    reinterpret_cast<float4*>(out)[i] = s;
}

// ---------------- xproj split-K with fused depthwise conv + SiLU ----------------
// 32 K-slices of 64 (grid 32x32 = 1024 blocks = 4/CU).
__global__ __launch_bounds__(256) void xproj_splitk(
    const unsigned short* __restrict__ xz,
    const float* __restrict__ cw,
    const float* __restrict__ cb,
    const float* __restrict__ B,
    unsigned short* __restrict__ u,
    float* __restrict__ part)
{
    __shared__ float As[16][68];
    __shared__ float Bs[16][100];
    int tid = threadIdx.x;
    int m0 = blockIdx.x * 64;
    int k0 = blockIdx.y * 64;
    int tx = tid & 15;
    int ty = tid >> 4;
    float acc[4][6] = {};
    int arow = tid >> 2, akg = (tid & 3) << 2;
    int brow1 = (256 + tid) >> 2, bkg1 = ((256 + tid) & 3) << 2;
    int m = m0 + arow;
    int l = m & 1023;

    for (int ks = 0; ks < 64; ks += 16) {
        int e0 = k0 + ks + akg;
        // --- fused conv+silu for 4 consecutive e at row m ---
        float xv[4][4];   // [kk][j]
        #pragma unroll
        for (int kk = 0; kk < 4; ++kk) {
            ushort4 t = make_ushort4(0, 0, 0, 0);
            if (l - 3 + kk >= 0)
                t = *reinterpret_cast<const ushort4*>(xz + (size_t)(m - 3 + kk) * 4096 + e0);
            xv[kk][0] = bfb(t.x); xv[kk][1] = bfb(t.y);
            xv[kk][2] = bfb(t.z); xv[kk][3] = bfb(t.w);
        }
        float4 cbv = *reinterpret_cast<const float4*>(cb + e0);
        float cbs[4] = { cbv.x, cbv.y, cbv.z, cbv.w };
        float res[4];
        #pragma unroll
        for (int j = 0; j < 4; ++j) {
            float4 w = *reinterpret_cast<const float4*>(cw + (size_t)(e0 + j) * 4);
            float a = cbs[j];
            a = fmaf(w.x, xv[0][j], a);
            a = fmaf(w.y, xv[1][j], a);
            a = fmaf(w.z, xv[2][j], a);
            a = fmaf(w.w, xv[3][j], a);
            res[j] = siluf(a);
        }
        ushort4 uo = { f2bf(res[0]), f2bf(res[1]), f2bf(res[2]), f2bf(res[3]) };
        *reinterpret_cast<ushort4*>(u + (size_t)m * 2048 + e0) = uo;

        // --- B (w_xproj) loads ---
        float4 bv0 = make_float4(0.f, 0.f, 0.f, 0.f), bv1 = bv0;
        if (arow < 96)  bv0 = *reinterpret_cast<const float4*>(B + (size_t)arow * 2048 + k0 + ks + akg);
        if (brow1 < 96) bv1 = *reinterpret_cast<const float4*>(B + (size_t)brow1 * 2048 + k0 + ks + bkg1);
        __syncthreads();
        As[akg + 0][arow] = res[0]; As[akg + 1][arow] = res[1];
        As[akg + 2][arow] = res[2]; As[akg + 3][arow] = res[3];
        if (arow < 96) {
            Bs[akg + 0][arow] = bv0.x; Bs[akg + 1][arow] = bv0.y;
            Bs[akg + 2][arow] = bv0.z; Bs[akg + 3][arow] = bv0.w;
        }
        if (brow1 < 96) {
            Bs[bkg1 + 0][brow1] = bv1.x; Bs[bkg1 + 1][brow1] = bv1.y;
            Bs[bkg1 + 2][brow1] = bv1.z; Bs[bkg1 + 3][brow1] = bv1.w;
        }
        __syncthreads();
        #pragma unroll
        for (int k = 0; k < 16; ++k) {
            float aa[4], bb[6];
            #pragma unroll
            for (int i = 0; i < 4; ++i) aa[i] = As[k][ty * 4 + i];
            #pragma unroll
            for (int j = 0; j < 6; ++j) bb[j] = Bs[k][tx * 6 + j];
            #pragma unroll
            for (int i = 0; i < 4; ++i)
                #pragma unroll
                for (int j = 0; j < 6; ++j)
                    acc[i][j] = fmaf(aa[i], bb[j], acc[i][j]);
        }
    }
    float* p = part + (size_t)blockIdx.y * 196608;
    #pragma unroll
    for (int i = 0; i < 4; ++i)
        #pragma unroll
        for (int j = 0; j < 6; ++j)
            p[(size_t)(m0 + ty * 4 + i) * 96 + tx * 6 + j] = acc[i][j];
}

// reduce 32 partials -> xdbl fp32
__global__ __launch_bounds__(256) void xproj_reduce(
    const float* __restrict__ part, float* __restrict__ xdbl)
{
    int i = blockIdx.x * 256 + threadIdx.x;   // 196608
    float s = 0.f;
    #pragma unroll
    for (int sd = 0; sd < 32; ++sd) s += part[(size_t)sd * 196608 + i];
    xdbl[i] = s;
}

// ---- fused dt tile: dtl[16 l][128 e] = softplus(bf16(xdbl[:, :64]) @ w_dt^T + b_dt)
// 4 MFMAs per wave (2 e-frags x 2 k); bf16-rounded result in LDS.
// softplus via native __logf(1+__expf) -- log1pf is a ~25-inst libm poly.
static __device__ __forceinline__ void dt_tile16(
    const float* __restrict__ xdbl, const unsigned short* __restrict__ w_dt_b,
    const float* __restrict__ b_dt, size_t rbase, int et,
    int lane, int wave, float dtl[LC][128])
{
    int frow = lane & 15, fq = lane >> 4;
    bf16x8 af[2];
    #pragma unroll
    for (int kk = 0; kk < 2; ++kk) {
        const float* ap = xdbl + (rbase + frow) * 96 + kk * 32 + fq * 8;
        float4 a0 = *reinterpret_cast<const float4*>(ap);
        float4 a1 = *reinterpret_cast<const float4*>(ap + 4);
        bf16x8 t;
        t[0] = (short)f2bf(a0.x); t[1] = (short)f2bf(a0.y);
        t[2] = (short)f2bf(a0.z); t[3] = (short)f2bf(a0.w);
        t[4] = (short)f2bf(a1.x); t[5] = (short)f2bf(a1.y);
        t[6] = (short)f2bf(a1.z); t[7] = (short)f2bf(a1.w);
        af[kk] = t;
    }
    f32x4 dacc[2] = {};
    #pragma unroll
    for (int j = 0; j < 2; ++j)
        #pragma unroll
        for (int kk = 0; kk < 2; ++kk) {
            int row_e = et * 128 + wave * 32 + j * 16 + frow;
            bf16x8 bfr = *reinterpret_cast<const bf16x8*>(
                w_dt_b + (size_t)row_e * 64 + kk * 32 + fq * 8);
            dacc[j] = __builtin_amdgcn_mfma_f32_16x16x32_bf16(af[kk], bfr, dacc[j], 0, 0, 0);
        }
    int cn = lane & 15, rq = (lane >> 4) * 4;
    #pragma unroll
    for (int j = 0; j < 2; ++j)
        #pragma unroll
        for (int r = 0; r < 4; ++r) {
            int row = rq + r;                      // 0..15 (l)
            int col = wave * 32 + j * 16 + cn;     // 0..127 (e)
            float v = dacc[j][r] + b_dt[et * 128 + col];
            float ex = __expf(v);
            v = (v > 20.f) ? v : __logf(1.f + ex);
            dtl[row][col] = bfb(f2bf(v));
        }
}

// ---------------- Chunked selective scan: 2 threads/channel, 8 states ----------
// grid 2048 = (b:2) x (et:16) x (c:64); 256 threads = 128 ch x 2 ngroups.
// 8 blocks/CU. B (and C) chunk rows staged in LDS; u preloaded into regs.
// part1 P via exp(A*S) identity (S = chunk cumsum of dt).
__global__ __launch_bounds__(256) void scan_part1(
    const unsigned short* __restrict__ u,
    const float* __restrict__ xdbl,
    const unsigned short* __restrict__ w_dt_b,
    const float* __restrict__ b_dt,
    const float* __restrict__ a_log,
    float* __restrict__ hpart,
    float* __restrict__ Aprod)
{
    __shared__ float dtl[LC][128];
    __shared__ float Bl[LC][16];
    int tid = threadIdx.x;
    int lane = tid & 63, wave = tid >> 6;
    int bid = blockIdx.x;
    int c = bid & 63, et = (bid >> 6) & 15, b = bid >> 10;
    int ch = tid >> 1, ng = tid & 1;
    int e = et * 128 + ch;
    size_t rbase = (size_t)b * 1024 + c * LC;

    // stage B rows: 16 l x 16 states, one float per thread
    Bl[tid >> 4][tid & 15] = xdbl[(rbase + (tid >> 4)) * 96 + 64 + (tid & 15)];

    dt_tile16(xdbl, w_dt_b, b_dt, rbase, et, lane, wave, dtl);

    float A[8];
    {
        float4 a0 = *reinterpret_cast<const float4*>(a_log + (size_t)e * 16 + ng * 8);
        float4 a1 = *reinterpret_cast<const float4*>(a_log + (size_t)e * 16 + ng * 8 + 4);
        A[0] = -__expf(a0.x); A[1] = -__expf(a0.y);
        A[2] = -__expf(a0.z); A[3] = -__expf(a0.w);
        A[4] = -__expf(a1.x); A[5] = -__expf(a1.y);
        A[6] = -__expf(a1.z); A[7] = -__expf(a1.w);
    }
    float h[8];
    #pragma unroll
    for (int n = 0; n < 8; ++n) h[n] = 0.f;
    float S = 0.f;

    // preload u chunk into regs: batch the 16 loads, overlap all latency
    const unsigned short* u_p = u + rbase * 2048 + e;
    float uc[LC];
    #pragma unroll
    for (int l = 0; l < LC; ++l) uc[l] = bfb(u_p[(size_t)l * 2048]);

    __syncthreads();
    #pragma unroll
    for (int l = 0; l < LC; ++l) {
        float dtv = dtl[l][ch];
        float4 b0 = *reinterpret_cast<const float4*>(&Bl[l][ng * 8]);
        float4 b1 = *reinterpret_cast<const float4*>(&Bl[l][ng * 8 + 4]);
        float Bv[8] = { b0.x, b0.y, b0.z, b0.w, b1.x, b1.y, b1.z, b1.w };
        float du = dtv * uc[l];
        S += dtv;
        #pragma unroll
        for (int n = 0; n < 8; ++n) {
            float d = __expf(dtv * A[n]);
            h[n] = fmaf(d, h[n], du * Bv[n]);
        }
    }
    float P[8];
    #pragma unroll
    for (int n = 0; n < 8; ++n) P[n] = __expf(A[n] * S);

    size_t oidx = (size_t)c * 65536 + ((size_t)b * 2048 + e) * 16 + ng * 8;
    *reinterpret_cast<float4*>(hpart + oidx)     = make_float4(h[0], h[1], h[2], h[3]);
    *reinterpret_cast<float4*>(hpart + oidx + 4) = make_float4(h[4], h[5], h[6], h[7]);
    *reinterpret_cast<float4*>(Aprod + oidx)     = make_float4(P[0], P[1], P[2], P[3]);
    *reinterpret_cast<float4*>(Aprod + oidx + 4) = make_float4(P[4], P[5], P[6], P[7]);
}

// 65536 scalar chains, 1 float/thread -> 256 blocks (all CUs busy)
__global__ __launch_bounds__(256) void scan_combine(
    const float* __restrict__ hpart,
    const float* __restrict__ Aprod,
    float* __restrict__ hinit)
{
    int t = blockIdx.x * 256 + threadIdx.x;   // 65536 threads x 1 float
    float h = 0.f;
    #pragma unroll 8
    for (int c = 0; c < NCHUNK; ++c) {
        hinit[(size_t)c * 65536 + t] = h;
        float P  = Aprod[(size_t)c * 65536 + t];
        float hp = hpart[(size_t)c * 65536 + t];
        h = fmaf(P, h, hp);
    }
}

__global__ __launch_bounds__(256) void scan_part2(
    const unsigned short* __restrict__ u,
    const float* __restrict__ xdbl,
    const unsigned short* __restrict__ w_dt_b,
    const float* __restrict__ b_dt,
    const unsigned short* __restrict__ xz,
    const float* __restrict__ a_log,
    const float* __restrict__ d_skip,
    const float* __restrict__ hinit,
    unsigned short* __restrict__ y)
{
    __shared__ float dtl[LC][128];
    __shared__ float BCl[LC][32];
    int tid = threadIdx.x;
    int lane = tid & 63, wave = tid >> 6;
    int bid = blockIdx.x;
    int c = bid & 63, et = (bid >> 6) & 15, b = bid >> 10;
    int ch = tid >> 1, ng = tid & 1;
    int e = et * 128 + ch;
    size_t rbase = (size_t)b * 1024 + c * LC;

    // stage B+C rows: 16 l x 32 floats, two floats per thread
    #pragma unroll
    for (int s = 0; s < 2; ++s) {
        int idx = s * 256 + tid;   // < 512
        BCl[idx >> 5][idx & 31] = xdbl[(rbase + (idx >> 5)) * 96 + 64 + (idx & 31)];
    }

    dt_tile16(xdbl, w_dt_b, b_dt, rbase, et, lane, wave, dtl);

    float A[8];
    {
        float4 a0 = *reinterpret_cast<const float4*>(a_log + (size_t)e * 16 + ng * 8);
        float4 a1 = *reinterpret_cast<const float4*>(a_log + (size_t)e * 16 + ng * 8 + 4);
        A[0] = -__expf(a0.x); A[1] = -__expf(a0.y);
        A[2] = -__expf(a0.z); A[3] = -__expf(a0.w);
        A[4] = -__expf(a1.x); A[5] = -__expf(a1.y);
        A[6] = -__expf(a1.z); A[7] = -__expf(a1.w);
    }
    float dsk = d_skip[e];
    float h[8];
    size_t oidx = (size_t)c * 65536 + ((size_t)b * 2048 + e) * 16 + ng * 8;
    {
        float4 h0 = *reinterpret_cast<const float4*>(hinit + oidx);
        float4 h1 = *reinterpret_cast<const float4*>(hinit + oidx + 4);
        h[0] = h0.x; h[1] = h0.y; h[2] = h0.z; h[3] = h0.w;
        h[4] = h1.x; h[5] = h1.y; h[6] = h1.z; h[7] = h1.w;
    }

    // preload u chunk into regs: batch the 16 loads, overlap all latency
    const unsigned short* u_p = u + rbase * 2048 + e;
    float uc[LC];
    #pragma unroll
    for (int l = 0; l < LC; ++l) uc[l] = bfb(u_p[(size_t)l * 2048]);

    const unsigned short* z_p = xz + rbase * 4096 + 2048 + e;
    unsigned short* y_p = y + rbase * 2048 + e;
    __syncthreads();
    #pragma unroll
    for (int l = 0; l < LC; ++l) {
        float dtv = dtl[l][ch];
        float4 b0 = *reinterpret_cast<const float4*>(&BCl[l][ng * 8]);
        float4 b1 = *reinterpret_cast<const float4*>(&BCl[l][ng * 8 + 4]);
        float4 c0 = *reinterpret_cast<const float4*>(&BCl[l][16 + ng * 8]);
        float4 c1 = *reinterpret_cast<const float4*>(&BCl[l][16 + ng * 8 + 4]);
        float Bv[8] = { b0.x, b0.y, b0.z, b0.w, b1.x, b1.y, b1.z, b1.w };
        float Cv[8] = { c0.x, c0.y, c0.z, c0.w, c1.x, c1.y, c1.z, c1.w };
        float du = dtv * uc[l];
        float p = 0.f;
        #pragma unroll
        for (int n = 0; n < 8; ++n) {
            float d = __expf(dtv * A[n]);
            h[n] = fmaf(d, h[n], du * Bv[n]);
            p = fmaf(h[n], Cv[n], p);
        }
        p += __shfl_xor(p, 1);
        if (ng == 0) {
            float zv = bfb(z_p[(size_t)l * 4096]);
            y_p[(size_t)l * 2048] = f2bf((p + uc[l] * dsk) * siluf(zv));
        }
    }
}

extern "C" void kernel_launch(void* const* d_in, const int* in_sizes, int n_in,
                              void* d_out, int out_size, void* d_ws, size_t ws_size,
                              hipStream_t stream) {
    const float* x       = (const float*)d_in[0];
    const float* ln_w    = (const float*)d_in[1];
    const float* ln_b    = (const float*)d_in[2];
    const float* w_in    = (const float*)d_in[3];
    const float* conv_w  = (const float*)d_in[4];
    const float* conv_b  = (const float*)d_in[5];
    const float* w_xproj = (const float*)d_in[6];
    const float* w_dt    = (const float*)d_in[7];
    const float* b_dt    = (const float*)d_in[8];
    const float* a_log   = (const float*)d_in[9];
    const float* d_skip  = (const float*)d_in[10];
    const float* w_out   = (const float*)d_in[11];
    float* out = (float*)d_out;

    float* ws = (float*)d_ws;
    unsigned short* xn_b    = (unsigned short*)(ws);
    unsigned short* xz_b    = (unsigned short*)(ws + 1048576);
    unsigned short* u_b     = (unsigned short*)(ws + 5242880);
    float* xdbl  = ws + 7340032;
    float* hpart = ws + 9633792;
    float* Aprod = ws + 13828096;
    float* hinit = ws + 18022400;
    unsigned short* y_b     = (unsigned short*)(ws + 22216704);
    unsigned short* w_in_b  = (unsigned short*)(ws + 24313856);
    unsigned short* w_out_b = (unsigned short*)(ws + 26411008);
    unsigned short* w_dt_b  = (unsigned short*)(ws + 27459584);
    float* xpart = ws + 9633792;    // 32x196608, aliases hpart/Aprod (dead until scan)
    float* opart = ws + 1048576;    // aliases xz_b..xdbl (dead after part2)

    // 0. weight converts + LayerNorm, one launch
    setup_kernel<<<8320, 256, 0, stream>>>(w_in, w_in_b, w_out, w_out_b, w_dt, w_dt_b,
                                           x, ln_w, ln_b, xn_b);
    // 1. xz = xn @ w_in^T  (2048 x 4096 x 1024)  MFMA 64x128 -> bf16
    gemm_bf16_nt<<<dim3(32, 32, 1), 256, 0, stream>>>(xn_b, 1024, w_in_b, 1024, 1024,
                                                      nullptr, xz_b, 4096, 3, 0);
    // 2+3. fused conv+silu -> u (side output) + x_dbl split-K partials (32 slices)
    xproj_splitk<<<dim3(32, 32), 256, 0, stream>>>(xz_b, conv_w, conv_b, w_xproj,
                                                   u_b, xpart);
    xproj_reduce<<<768, 256, 0, stream>>>(xpart, xdbl);
    // 4+5. chunked selective scan (LC=16, 64 chunks), 2 thr/channel, dt fused,
    //      B/C staged in LDS, u preloaded, native __expf
    scan_part1<<<2048, 256, 0, stream>>>(u_b, xdbl, w_dt_b, b_dt, a_log, hpart, Aprod);
    scan_combine<<<256, 256, 0, stream>>>(hpart, Aprod, hinit);
    scan_part2<<<2048, 256, 0, stream>>>(u_b, xdbl, w_dt_b, b_dt, xz_b, a_log,
                                         d_skip, hinit, y_b);
    // 6. out-proj split-K x4 (fp32 partials) + reduce(+residual)
    gemm_bf16_nt<<<dim3(8, 32, 4), 256, 0, stream>>>(y_b, 2048, w_out_b, 2048, 512,
                                                     opart, nullptr, 1024, 0, 2097152);
    out_reduce<<<2048, 256, 0, stream>>>(opart, x, out);
}

// Round 13
// 237.470 us; speedup vs baseline: 1.2150x; 1.0218x over previous
//
#include <hip/hip_runtime.h>
#include <hip/hip_bf16.h>

// MambaBlock: B=2, L=1024, dim=1024, d_inner=2048, DT_RANK=64, D_STATE=16
// Inputs fp32, output fp32. Intermediates xz/u/y bf16; scan state fp32.
// MFMA GEMMs: 64x128 tile, BK=32, 3-buf 2-ahead prefetch, counted vmcnt(3),
// XCD-aware block swizzle. conv+SiLU fused into xproj_splitk (32 K-slices).
// dt-GEMM fused into scan as a per-block 16x128 mini-MFMA (dtl in LDS).
// Scan: 2 threads/channel (8 states each), LC=16, NCHUNK=64 (8 blocks/CU),
// u/z/B/C chunk rows staged into LDS via coalesced 16B loads (kills the
// 16-32 scattered scalar global loads per thread), part1 P via exp(A*S),
// native __expf/__logf only.  9 dispatches total.
//
// ws layout (float units):
//   xn_b  (bf16 2048x1024) : @0          1,048,576
//   xz_b  (bf16 2048x4096) : @1,048,576  4,194,304   } opart (fp32 4x2,097,152)
//   u_b   (bf16 2048x2048) : @5,242,880  2,097,152   }   aliases xz_b..xdbl
//   xdbl  (fp32 2048x96)   : @7,340,032    196,608   }   dead after scan_part2
//   (gap)                  : @7,536,640  2,097,152   }
//   hpart (fp32 64x65536)  : @9,633,792  4,194,304   } xpart 32x196608=6.29M
//   Aprod (fp32 64x65536)  : @13,828,096 4,194,304   }   aliases hpart+Aprod
//   hinit (fp32 64x65536)  : @18,022,400 4,194,304   }   (dead until scan)
//   y_b   (bf16 2048x2048) : @22,216,704 2,097,152
//   w_in_b (bf16)          : @24,313,856 2,097,152
//   w_out_b(bf16)          : @26,411,008 1,048,576
//   w_dt_b (bf16)          : @27,459,584    65,536
// total < 27,590,656 fu = 110 MB (ws = 256 MiB)

#define LC 16
#define NCHUNK 64

typedef short bf16x8 __attribute__((ext_vector_type(8)));
typedef float f32x4  __attribute__((ext_vector_type(4)));

static __device__ __forceinline__ float siluf(float x) { return x / (1.f + __expf(-x)); }
static __device__ __forceinline__ unsigned short f2bf(float f) {
    unsigned int u = __float_as_uint(f);
    unsigned int r = (u + 0x7fffu + ((u >> 16) & 1u)) >> 16;
    return (unsigned short)r;
}
static __device__ __forceinline__ float bfb(unsigned short u) {
    return __uint_as_float(((unsigned int)u) << 16);
}
// async global->LDS, 16 B per lane; LDS dest = wave-uniform base + lane*16
static __device__ __forceinline__ void gload_lds16(const void* g, void* l) {
    __builtin_amdgcn_global_load_lds(
        (const __attribute__((address_space(1))) void*)g,
        (__attribute__((address_space(3))) void*)l, 16, 0, 0);
}

// ---------------- fused setup: weight converts + LayerNorm ----------------
// blocks [0,6272): w_in/w_out/w_dt fp32->bf16;  blocks [6272,8320): LN row m
__global__ __launch_bounds__(256) void setup_kernel(
    const float* __restrict__ w_in,  unsigned short* __restrict__ w_in_b,
    const float* __restrict__ w_out, unsigned short* __restrict__ w_out_b,
    const float* __restrict__ w_dt,  unsigned short* __restrict__ w_dt_b,
    const float* __restrict__ x,
    const float* __restrict__ ln_w,
    const float* __restrict__ ln_b,
    unsigned short* __restrict__ xn)
{
    int bid = blockIdx.x, tid = threadIdx.x;
    if (bid < 6272) {
        int i = bid * 256 + tid;
        const float* in; unsigned short* outp; int j;
        if (i < 1048576)      { in = w_in;  outp = w_in_b;  j = i; }
        else if (i < 1572864) { in = w_out; outp = w_out_b; j = i - 1048576; }
        else if (i < 1605632) { in = w_dt;  outp = w_dt_b;  j = i - 1572864; }
        else return;
        float4 v = reinterpret_cast<const float4*>(in)[j];
        ushort4 o = { f2bf(v.x), f2bf(v.y), f2bf(v.z), f2bf(v.w) };
        reinterpret_cast<ushort4*>(outp)[j] = o;
        return;
    }
    int m = bid - 6272;
    const float4* xr = reinterpret_cast<const float4*>(x) + (size_t)m * 256;
    float4 r = xr[tid];
    float f0 = r.x, f1 = r.y, f2 = r.z, f3 = r.w;
    float s  = f0 + f1 + f2 + f3;
    float s2 = f0*f0 + f1*f1 + f2*f2 + f3*f3;
    #pragma unroll
    for (int off = 32; off > 0; off >>= 1) {
        s  += __shfl_down(s, off);
        s2 += __shfl_down(s2, off);
    }
    __shared__ float red[8];
    if ((tid & 63) == 0) { red[tid >> 6] = s; red[4 + (tid >> 6)] = s2; }
    __syncthreads();
    float st = red[0] + red[1] + red[2] + red[3];
    float qt = red[4] + red[5] + red[6] + red[7];
    float mu   = st * (1.f / 1024.f);
    float var  = qt * (1.f / 1024.f) - mu * mu;
    float rstd = rsqrtf(var + 1e-5f);
    float4 wv = reinterpret_cast<const float4*>(ln_w)[tid];
    float4 bv = reinterpret_cast<const float4*>(ln_b)[tid];
    ushort4 o = { f2bf((f0 - mu) * rstd * wv.x + bv.x),
                  f2bf((f1 - mu) * rstd * wv.y + bv.y),
                  f2bf((f2 - mu) * rstd * wv.z + bv.z),
                  f2bf((f3 - mu) * rstd * wv.w + bv.w) };
    reinterpret_cast<ushort4*>(xn + (size_t)m * 1024)[tid] = o;
}

// ---------------- bf16 MFMA GEMM-NT, 64x128 tile, 3-buf counted-vmcnt ----------
// 4 waves in 2x2 grid over (M=64, N=128); each wave 32x64 (acc[2][4]).
// XCD swizzle: contiguous tile chunk per XCD (grid %8==0 -> bijective).
// ep: 0 = fp32 raw -> C; 3 = raw -> Cb bf16
__global__ __launch_bounds__(256) void gemm_bf16_nt(
    const unsigned short* __restrict__ A, int lda,
    const unsigned short* __restrict__ B, int ldb,
    int Kslice,
    float* __restrict__ C, unsigned short* __restrict__ Cb, int ldc,
    int ep, size_t Cstride)
{
    __shared__ short As[3 * 64 * 32];    // 12 KB
    __shared__ short Bs[3 * 128 * 32];   // 24 KB
    int tid = threadIdx.x;
    int z = blockIdx.z;
    A += (size_t)z * Kslice;
    B += (size_t)z * Kslice;
    C += (size_t)z * Cstride;

    // XCD-aware swizzle over (x,y) tile grid
    int gx = gridDim.x;
    int wg = blockIdx.y * gx + blockIdx.x;
    int nwg = gx * gridDim.y;
    int cpx = nwg >> 3;
    int swz = (wg & 7) * cpx + (wg >> 3);
    int bx = swz % gx, by = swz / gx;

    int m0 = by * 64, n0 = bx * 128;
    int lane = tid & 63, wave = tid >> 6;
    int wm = (wave >> 1) * 32, wn = (wave & 1) * 64;
    int frow = lane & 15, fq = lane >> 4;

    f32x4 acc[2][4] = {};

    int lrow = lane >> 2;
    int scol = (lane & 3) * 8;
    const unsigned short* AgL = A + (size_t)(m0 + wave * 16 + lrow) * lda + scol;
    const unsigned short* BgL = B + (size_t)(n0 + wave * 16 + lrow) * ldb + scol;
    int aoff = (wave * 16) * 32;   // shorts
    int boff = (wave * 16) * 32;

    // prologue: stage buffers 0 and 1 (6 loads in flight per wave)
    #pragma unroll
    for (int p = 0; p < 2; ++p) {
        int nk = p * 32;
        gload_lds16(AgL + nk,                    As + p * 2048 + aoff);
        gload_lds16(BgL + nk,                    Bs + p * 4096 + boff);
        gload_lds16(BgL + (size_t)64 * ldb + nk, Bs + p * 4096 + boff + 64 * 32);
    }

    int cur = 0;
    for (int k0 = 0; k0 < Kslice; k0 += 32) {
        if (k0 + 32 < Kslice) {
            asm volatile("s_waitcnt vmcnt(3) lgkmcnt(0)" ::: "memory");
        } else {
            asm volatile("s_waitcnt vmcnt(0) lgkmcnt(0)" ::: "memory");
        }
        __builtin_amdgcn_s_barrier();
        int nk = k0 + 64;
        if (nk < Kslice) {
            int stg = cur - 1; if (stg < 0) stg = 2;   // (cur+2)%3
            gload_lds16(AgL + nk,                    As + stg * 2048 + aoff);
            gload_lds16(BgL + nk,                    Bs + stg * 4096 + boff);
            gload_lds16(BgL + (size_t)64 * ldb + nk, Bs + stg * 4096 + boff + 64 * 32);
        }
        const short* Ac = As + cur * 2048;
        const short* Bc = Bs + cur * 4096;
        bf16x8 af[2], bfr[4];
        #pragma unroll
        for (int i = 0; i < 2; ++i)
            af[i] = *reinterpret_cast<const bf16x8*>(Ac + (wm + i * 16 + frow) * 32 + fq * 8);
        #pragma unroll
        for (int j = 0; j < 4; ++j)
            bfr[j] = *reinterpret_cast<const bf16x8*>(Bc + (wn + j * 16 + frow) * 32 + fq * 8);
        #pragma unroll
        for (int i = 0; i < 2; ++i)
            #pragma unroll
            for (int j = 0; j < 4; ++j)
                acc[i][j] = __builtin_amdgcn_mfma_f32_16x16x32_bf16(af[i], bfr[j], acc[i][j], 0, 0, 0);
        cur = (cur == 2) ? 0 : cur + 1;
    }

    int cn = lane & 15, rq = (lane >> 4) * 4;
    #pragma unroll
    for (int i = 0; i < 2; ++i) {
        #pragma unroll
        for (int j = 0; j < 4; ++j) {
            #pragma unroll
            for (int r = 0; r < 4; ++r) {
                int row = m0 + wm + i * 16 + rq + r;
                int col = n0 + wn + j * 16 + cn;
                float v = acc[i][j][r];
                if (ep == 0) {
                    C[(size_t)row * ldc + col] = v;
                } else {
                    Cb[(size_t)row * ldc + col] = f2bf(v);
                }
            }
        }
    }
}

// ---------------- out = x + sum_z part[z] ----------------
__global__ __launch_bounds__(256) void out_reduce(
    const float* __restrict__ part, const float* __restrict__ x,
    float* __restrict__ out)
{
    int i = blockIdx.x * 256 + threadIdx.x;
    float4 s = reinterpret_cast<const float4*>(x)[i];
    #pragma unroll
    for (int z = 0; z < 4; ++z) {
        float4 p = reinterpret_cast<const float4*>(part + (size_t)z * 2097152)[i];
        s.x += p.x; s.y += p.y; s.z += p.z; s.w += p.w;
    }
    reinterpret_cast<float4*>(out)[i] = s;
}

// ---------------- xproj split-K with fused depthwise conv + SiLU ----------------
// 32 K-slices of 64 (grid 32x32 = 1024 blocks = 4/CU).
__global__ __launch_bounds__(256) void xproj_splitk(
    const unsigned short* __restrict__ xz,
    const float* __restrict__ cw,
    const float* __restrict__ cb,
    const float* __restrict__ B,
    unsigned short* __restrict__ u,
    float* __restrict__ part)
{
    __shared__ float As[16][68];
    __shared__ float Bs[16][100];
    int tid = threadIdx.x;
    int m0 = blockIdx.x * 64;
    int k0 = blockIdx.y * 64;
    int tx = tid & 15;
    int ty = tid >> 4;
    float acc[4][6] = {};
    int arow = tid >> 2, akg = (tid & 3) << 2;
    int brow1 = (256 + tid) >> 2, bkg1 = ((256 + tid) & 3) << 2;
    int m = m0 + arow;
    int l = m & 1023;

    for (int ks = 0; ks < 64; ks += 16) {
        int e0 = k0 + ks + akg;
        // --- fused conv+silu for 4 consecutive e at row m ---
        float xv[4][4];   // [kk][j]
        #pragma unroll
        for (int kk = 0; kk < 4; ++kk) {
            ushort4 t = make_ushort4(0, 0, 0, 0);
            if (l - 3 + kk >= 0)
                t = *reinterpret_cast<const ushort4*>(xz + (size_t)(m - 3 + kk) * 4096 + e0);
            xv[kk][0] = bfb(t.x); xv[kk][1] = bfb(t.y);
            xv[kk][2] = bfb(t.z); xv[kk][3] = bfb(t.w);
        }
        float4 cbv = *reinterpret_cast<const float4*>(cb + e0);
        float cbs[4] = { cbv.x, cbv.y, cbv.z, cbv.w };
        float res[4];
        #pragma unroll
        for (int j = 0; j < 4; ++j) {
            float4 w = *reinterpret_cast<const float4*>(cw + (size_t)(e0 + j) * 4);
            float a = cbs[j];
            a = fmaf(w.x, xv[0][j], a);
            a = fmaf(w.y, xv[1][j], a);
            a = fmaf(w.z, xv[2][j], a);
            a = fmaf(w.w, xv[3][j], a);
            res[j] = siluf(a);
        }
        ushort4 uo = { f2bf(res[0]), f2bf(res[1]), f2bf(res[2]), f2bf(res[3]) };
        *reinterpret_cast<ushort4*>(u + (size_t)m * 2048 + e0) = uo;

        // --- B (w_xproj) loads ---
        float4 bv0 = make_float4(0.f, 0.f, 0.f, 0.f), bv1 = bv0;
        if (arow < 96)  bv0 = *reinterpret_cast<const float4*>(B + (size_t)arow * 2048 + k0 + ks + akg);
        if (brow1 < 96) bv1 = *reinterpret_cast<const float4*>(B + (size_t)brow1 * 2048 + k0 + ks + bkg1);
        __syncthreads();
        As[akg + 0][arow] = res[0]; As[akg + 1][arow] = res[1];
        As[akg + 2][arow] = res[2]; As[akg + 3][arow] = res[3];
        if (arow < 96) {
            Bs[akg + 0][arow] = bv0.x; Bs[akg + 1][arow] = bv0.y;
            Bs[akg + 2][arow] = bv0.z; Bs[akg + 3][arow] = bv0.w;
        }
        if (brow1 < 96) {
            Bs[bkg1 + 0][brow1] = bv1.x; Bs[bkg1 + 1][brow1] = bv1.y;
            Bs[bkg1 + 2][brow1] = bv1.z; Bs[bkg1 + 3][brow1] = bv1.w;
        }
        __syncthreads();
        #pragma unroll
        for (int k = 0; k < 16; ++k) {
            float aa[4], bb[6];
            #pragma unroll
            for (int i = 0; i < 4; ++i) aa[i] = As[k][ty * 4 + i];
            #pragma unroll
            for (int j = 0; j < 6; ++j) bb[j] = Bs[k][tx * 6 + j];
            #pragma unroll
            for (int i = 0; i < 4; ++i)
                #pragma unroll
                for (int j = 0; j < 6; ++j)
                    acc[i][j] = fmaf(aa[i], bb[j], acc[i][j]);
        }
    }
    float* p = part + (size_t)blockIdx.y * 196608;
    #pragma unroll
    for (int i = 0; i < 4; ++i)
        #pragma unroll
        for (int j = 0; j < 6; ++j)
            p[(size_t)(m0 + ty * 4 + i) * 96 + tx * 6 + j] = acc[i][j];
}

// reduce 32 partials -> xdbl fp32
__global__ __launch_bounds__(256) void xproj_reduce(
    const float* __restrict__ part, float* __restrict__ xdbl)
{
    int i = blockIdx.x * 256 + threadIdx.x;   // 196608
    float s = 0.f;
    #pragma unroll
    for (int sd = 0; sd < 32; ++sd) s += part[(size_t)sd * 196608 + i];
    xdbl[i] = s;
}

// ---- fused dt tile: dtl[16 l][128 e] = softplus(bf16(xdbl[:, :64]) @ w_dt^T + b_dt)
// 4 MFMAs per wave (2 e-frags x 2 k); bf16-rounded result in LDS.
// softplus via native __logf(1+__expf).
static __device__ __forceinline__ void dt_tile16(
    const float* __restrict__ xdbl, const unsigned short* __restrict__ w_dt_b,
    const float* __restrict__ b_dt, size_t rbase, int et,
    int lane, int wave, float dtl[LC][128])
{
    int frow = lane & 15, fq = lane >> 4;
    bf16x8 af[2];
    #pragma unroll
    for (int kk = 0; kk < 2; ++kk) {
        const float* ap = xdbl + (rbase + frow) * 96 + kk * 32 + fq * 8;
        float4 a0 = *reinterpret_cast<const float4*>(ap);
        float4 a1 = *reinterpret_cast<const float4*>(ap + 4);
        bf16x8 t;
        t[0] = (short)f2bf(a0.x); t[1] = (short)f2bf(a0.y);
        t[2] = (short)f2bf(a0.z); t[3] = (short)f2bf(a0.w);
        t[4] = (short)f2bf(a1.x); t[5] = (short)f2bf(a1.y);
        t[6] = (short)f2bf(a1.z); t[7] = (short)f2bf(a1.w);
        af[kk] = t;
    }
    f32x4 dacc[2] = {};
    #pragma unroll
    for (int j = 0; j < 2; ++j)
        #pragma unroll
        for (int kk = 0; kk < 2; ++kk) {
            int row_e = et * 128 + wave * 32 + j * 16 + frow;
            bf16x8 bfr = *reinterpret_cast<const bf16x8*>(
                w_dt_b + (size_t)row_e * 64 + kk * 32 + fq * 8);
            dacc[j] = __builtin_amdgcn_mfma_f32_16x16x32_bf16(af[kk], bfr, dacc[j], 0, 0, 0);
        }
    int cn = lane & 15, rq = (lane >> 4) * 4;
    #pragma unroll
    for (int j = 0; j < 2; ++j)
        #pragma unroll
        for (int r = 0; r < 4; ++r) {
            int row = rq + r;                      // 0..15 (l)
            int col = wave * 32 + j * 16 + cn;     // 0..127 (e)
            float v = dacc[j][r] + b_dt[et * 128 + col];
            float ex = __expf(v);
            v = (v > 20.f) ? v : __logf(1.f + ex);
            dtl[row][col] = bfb(f2bf(v));
        }
}

// ---------------- Chunked selective scan: 2 threads/channel, 8 states ----------
// grid 2048 = (b:2) x (et:16) x (c:64); 256 threads = 128 ch x 2 ngroups.
// 8 blocks/CU. u/B rows staged into LDS via coalesced 16B loads; inner loop
// is pure LDS + VALU. part1 P via exp(A*S) identity.
__global__ __launch_bounds__(256) void scan_part1(
    const unsigned short* __restrict__ u,
    const float* __restrict__ xdbl,
    const unsigned short* __restrict__ w_dt_b,
    const float* __restrict__ b_dt,
    const float* __restrict__ a_log,
    float* __restrict__ hpart,
    float* __restrict__ Aprod)
{
    __shared__ float dtl[LC][128];
    __shared__ float Bl[LC][16];
    __shared__ unsigned short ul[LC][128];
    int tid = threadIdx.x;
    int lane = tid & 63, wave = tid >> 6;
    int bid = blockIdx.x;
    int c = bid & 63, et = (bid >> 6) & 15, b = bid >> 10;
    int ch = tid >> 1, ng = tid & 1;
    int e = et * 128 + ch;
    size_t rbase = (size_t)b * 1024 + c * LC;

    // stage u rows: 16 rows x 128 shorts; thread t -> row t>>4, 8 shorts (16B)
    {
        int r = tid >> 4, o = (tid & 15) * 8;
        *reinterpret_cast<float4*>(&ul[r][o]) =
            *reinterpret_cast<const float4*>(u + (rbase + r) * 2048 + et * 128 + o);
    }
    // stage B rows: 16 l x 16 states, one float per thread
    Bl[tid >> 4][tid & 15] = xdbl[(rbase + (tid >> 4)) * 96 + 64 + (tid & 15)];

    dt_tile16(xdbl, w_dt_b, b_dt, rbase, et, lane, wave, dtl);

    float A[8];
    {
        float4 a0 = *reinterpret_cast<const float4*>(a_log + (size_t)e * 16 + ng * 8);
        float4 a1 = *reinterpret_cast<const float4*>(a_log + (size_t)e * 16 + ng * 8 + 4);
        A[0] = -__expf(a0.x); A[1] = -__expf(a0.y);
        A[2] = -__expf(a0.z); A[3] = -__expf(a0.w);
        A[4] = -__expf(a1.x); A[5] = -__expf(a1.y);
        A[6] = -__expf(a1.z); A[7] = -__expf(a1.w);
    }
    float h[8];
    #pragma unroll
    for (int n = 0; n < 8; ++n) h[n] = 0.f;
    float S = 0.f;

    __syncthreads();
    #pragma unroll
    for (int l = 0; l < LC; ++l) {
        float dtv = dtl[l][ch];
        float u_c = bfb(ul[l][ch]);
        float4 b0 = *reinterpret_cast<const float4*>(&Bl[l][ng * 8]);
        float4 b1 = *reinterpret_cast<const float4*>(&Bl[l][ng * 8 + 4]);
        float Bv[8] = { b0.x, b0.y, b0.z, b0.w, b1.x, b1.y, b1.z, b1.w };
        float du = dtv * u_c;
        S += dtv;
        #pragma unroll
        for (int n = 0; n < 8; ++n) {
            float d = __expf(dtv * A[n]);
            h[n] = fmaf(d, h[n], du * Bv[n]);
        }
    }
    float P[8];
    #pragma unroll
    for (int n = 0; n < 8; ++n) P[n] = __expf(A[n] * S);

    size_t oidx = (size_t)c * 65536 + ((size_t)b * 2048 + e) * 16 + ng * 8;
    *reinterpret_cast<float4*>(hpart + oidx)     = make_float4(h[0], h[1], h[2], h[3]);
    *reinterpret_cast<float4*>(hpart + oidx + 4) = make_float4(h[4], h[5], h[6], h[7]);
    *reinterpret_cast<float4*>(Aprod + oidx)     = make_float4(P[0], P[1], P[2], P[3]);
    *reinterpret_cast<float4*>(Aprod + oidx + 4) = make_float4(P[4], P[5], P[6], P[7]);
}

// 65536 scalar chains, 1 float/thread -> 256 blocks (all CUs busy)
__global__ __launch_bounds__(256) void scan_combine(
    const float* __restrict__ hpart,
    const float* __restrict__ Aprod,
    float* __restrict__ hinit)
{
    int t = blockIdx.x * 256 + threadIdx.x;   // 65536 threads x 1 float
    float h = 0.f;
    #pragma unroll 8
    for (int c = 0; c < NCHUNK; ++c) {
        hinit[(size_t)c * 65536 + t] = h;
        float P  = Aprod[(size_t)c * 65536 + t];
        float hp = hpart[(size_t)c * 65536 + t];
        h = fmaf(P, h, hp);
    }
}

__global__ __launch_bounds__(256) void scan_part2(
    const unsigned short* __restrict__ u,
    const float* __restrict__ xdbl,
    const unsigned short* __restrict__ w_dt_b,
    const float* __restrict__ b_dt,
    const unsigned short* __restrict__ xz,
    const float* __restrict__ a_log,
    const float* __restrict__ d_skip,
    const float* __restrict__ hinit,
    unsigned short* __restrict__ y)
{
    __shared__ float dtl[LC][128];
    __shared__ float BCl[LC][32];
    __shared__ unsigned short ul[LC][128];
    __shared__ unsigned short zl[LC][128];
    int tid = threadIdx.x;
    int lane = tid & 63, wave = tid >> 6;
    int bid = blockIdx.x;
    int c = bid & 63, et = (bid >> 6) & 15, b = bid >> 10;
    int ch = tid >> 1, ng = tid & 1;
    int e = et * 128 + ch;
    size_t rbase = (size_t)b * 1024 + c * LC;

    // stage u and z rows: 16 rows x 128 shorts each, one 16B load per buffer
    {
        int r = tid >> 4, o = (tid & 15) * 8;
        *reinterpret_cast<float4*>(&ul[r][o]) =
            *reinterpret_cast<const float4*>(u + (rbase + r) * 2048 + et * 128 + o);
        *reinterpret_cast<float4*>(&zl[r][o]) =
            *reinterpret_cast<const float4*>(xz + (rbase + r) * 4096 + 2048 + et * 128 + o);
    }
    // stage B+C rows: 16 l x 32 floats, two floats per thread
    #pragma unroll
    for (int s = 0; s < 2; ++s) {
        int idx = s * 256 + tid;   // < 512
        BCl[idx >> 5][idx & 31] = xdbl[(rbase + (idx >> 5)) * 96 + 64 + (idx & 31)];
    }

    dt_tile16(xdbl, w_dt_b, b_dt, rbase, et, lane, wave, dtl);

    float A[8];
    {
        float4 a0 = *reinterpret_cast<const float4*>(a_log + (size_t)e * 16 + ng * 8);
        float4 a1 = *reinterpret_cast<const float4*>(a_log + (size_t)e * 16 + ng * 8 + 4);
        A[0] = -__expf(a0.x); A[1] = -__expf(a0.y);
        A[2] = -__expf(a0.z); A[3] = -__expf(a0.w);
        A[4] = -__expf(a1.x); A[5] = -__expf(a1.y);
        A[6] = -__expf(a1.z); A[7] = -__expf(a1.w);
    }
    float dsk = d_skip[e];
    float h[8];
    size_t oidx = (size_t)c * 65536 + ((size_t)b * 2048 + e) * 16 + ng * 8;
    {
        float4 h0 = *reinterpret_cast<const float4*>(hinit + oidx);
        float4 h1 = *reinterpret_cast<const float4*>(hinit + oidx + 4);
        h[0] = h0.x; h[1] = h0.y; h[2] = h0.z; h[3] = h0.w;
        h[4] = h1.x; h[5] = h1.y; h[6] = h1.z; h[7] = h1.w;
    }

    unsigned short* y_p = y + rbase * 2048 + e;
    __syncthreads();
    #pragma unroll
    for (int l = 0; l < LC; ++l) {
        float dtv = dtl[l][ch];
        float u_c = bfb(ul[l][ch]);
        float4 b0 = *reinterpret_cast<const float4*>(&BCl[l][ng * 8]);
        float4 b1 = *reinterpret_cast<const float4*>(&BCl[l][ng * 8 + 4]);
        float4 c0 = *reinterpret_cast<const float4*>(&BCl[l][16 + ng * 8]);
        float4 c1 = *reinterpret_cast<const float4*>(&BCl[l][16 + ng * 8 + 4]);
        float Bv[8] = { b0.x, b0.y, b0.z, b0.w, b1.x, b1.y, b1.z, b1.w };
        float Cv[8] = { c0.x, c0.y, c0.z, c0.w, c1.x, c1.y, c1.z, c1.w };
        float du = dtv * u_c;
        float p = 0.f;
        #pragma unroll
        for (int n = 0; n < 8; ++n) {
            float d = __expf(dtv * A[n]);
            h[n] = fmaf(d, h[n], du * Bv[n]);
            p = fmaf(h[n], Cv[n], p);
        }
        p += __shfl_xor(p, 1);
        if (ng == 0) {
            float zv = bfb(zl[l][ch]);
            y_p[(size_t)l * 2048] = f2bf((p + u_c * dsk) * siluf(zv));
        }
    }
}

extern "C" void kernel_launch(void* const* d_in, const int* in_sizes, int n_in,
                              void* d_out, int out_size, void* d_ws, size_t ws_size,
                              hipStream_t stream) {
    const float* x       = (const float*)d_in[0];
    const float* ln_w    = (const float*)d_in[1];
    const float* ln_b    = (const float*)d_in[2];
    const float* w_in    = (const float*)d_in[3];
    const float* conv_w  = (const float*)d_in[4];
    const float* conv_b  = (const float*)d_in[5];
    const float* w_xproj = (const float*)d_in[6];
    const float* w_dt    = (const float*)d_in[7];
    const float* b_dt    = (const float*)d_in[8];
    const float* a_log   = (const float*)d_in[9];
    const float* d_skip  = (const float*)d_in[10];
    const float* w_out   = (const float*)d_in[11];
    float* out = (float*)d_out;

    float* ws = (float*)d_ws;
    unsigned short* xn_b    = (unsigned short*)(ws);
    unsigned short* xz_b    = (unsigned short*)(ws + 1048576);
    unsigned short* u_b     = (unsigned short*)(ws + 5242880);
    float* xdbl  = ws + 7340032;
    float* hpart = ws + 9633792;
    float* Aprod = ws + 13828096;
    float* hinit = ws + 18022400;
    unsigned short* y_b     = (unsigned short*)(ws + 22216704);
    unsigned short* w_in_b  = (unsigned short*)(ws + 24313856);
    unsigned short* w_out_b = (unsigned short*)(ws + 26411008);
    unsigned short* w_dt_b  = (unsigned short*)(ws + 27459584);
    float* xpart = ws + 9633792;    // 32x196608, aliases hpart/Aprod (dead until scan)
    float* opart = ws + 1048576;    // aliases xz_b..xdbl (dead after part2)

    // 0. weight converts + LayerNorm, one launch
    setup_kernel<<<8320, 256, 0, stream>>>(w_in, w_in_b, w_out, w_out_b, w_dt, w_dt_b,
                                           x, ln_w, ln_b, xn_b);
    // 1. xz = xn @ w_in^T  (2048 x 4096 x 1024)  MFMA 64x128 -> bf16
    gemm_bf16_nt<<<dim3(32, 32, 1), 256, 0, stream>>>(xn_b, 1024, w_in_b, 1024, 1024,
                                                      nullptr, xz_b, 4096, 3, 0);
    // 2+3. fused conv+silu -> u (side output) + x_dbl split-K partials (32 slices)
    xproj_splitk<<<dim3(32, 32), 256, 0, stream>>>(xz_b, conv_w, conv_b, w_xproj,
                                                   u_b, xpart);
    xproj_reduce<<<768, 256, 0, stream>>>(xpart, xdbl);
    // 4+5. chunked selective scan (LC=16, 64 chunks), 2 thr/channel, dt fused,
    //      u/z/B/C staged in LDS, native __expf
    scan_part1<<<2048, 256, 0, stream>>>(u_b, xdbl, w_dt_b, b_dt, a_log, hpart, Aprod);
    scan_combine<<<256, 256, 0, stream>>>(hpart, Aprod, hinit);
    scan_part2<<<2048, 256, 0, stream>>>(u_b, xdbl, w_dt_b, b_dt, xz_b, a_log,
                                         d_skip, hinit, y_b);
    // 6. out-proj split-K x4 (fp32 partials) + reduce(+residual)
    gemm_bf16_nt<<<dim3(8, 32, 4), 256, 0, stream>>>(y_b, 2048, w_out_b, 2048, 512,
                                                     opart, nullptr, 1024, 0, 2097152);
    out_reduce<<<2048, 256, 0, stream>>>(opart, x, out);
}